// Round 10
// baseline (409.387 us; speedup 1.0000x reference)
//
#include <hip/hip_runtime.h>
#include <hip/hip_bf16.h>
#include <math.h>

// ---------------------------------------------------------------------------
// MPI-NeRF style network renderer for MI355X (gfx950).
// R9: revert to R7 structure (16x16x32 MFMA, 248us mlp). Add: cross-layer
//     weight prefetch (regs, issued pre-barrier), venc precomputed in phase 1,
//     basis-MLP ping-pong into dead LDS regions (3 fewer barriers).
// ---------------------------------------------------------------------------

typedef _Float16 half2 __attribute__((ext_vector_type(2)));
typedef _Float16 half4 __attribute__((ext_vector_type(4)));
typedef _Float16 half8 __attribute__((ext_vector_type(8)));
typedef float f32x4 __attribute__((ext_vector_type(4)));

#if __has_builtin(__builtin_amdgcn_mfma_f32_16x16x32_f16)
#define MFMA32(a, b, c) __builtin_amdgcn_mfma_f32_16x16x32_f16((a), (b), (c), 0, 0, 0)
#else
#define MFMA32(a, b, c) (c)   // host-pass placeholder (never executed)
#endif

#define NPLANES 192
#define RAYS    1024
#define IMW     768
#define IMH     512

// fragment-order index into hbuf: point i (0..63), feature/column c (0..383)
// layout [pt(4)][kc(12)][g(4)][ln(16)][j(8)], strides 6144/512/128/8/1 halves
#define FR(i, c) ((((i) >> 4) * 6144) + (((c) >> 5) * 512) + ((((c) >> 3) & 3) * 128) \
                  + (((i) & 15) * 8) + ((c) & 7))

// sin(2*pi*rev) via HW: fract to [0,1) then v_sin
__device__ __forceinline__ float sin_rev(float rev) {
  float f, r;
  asm("v_fract_f32 %0, %1" : "=v"(f) : "v"(rev));
  asm("v_sin_f32 %0, %1" : "=v"(r) : "v"(f));
  return r;
}
__device__ __forceinline__ float exp2_fast(float x) {
  float r;
  asm("v_exp_f32 %0, %1" : "=v"(r) : "v"(x));
  return r;
}
__device__ __forceinline__ float rcp_fast(float x) {
  float r;
  asm("v_rcp_f32 %0, %1" : "=v"(r) : "v"(x));
  return r;
}
__device__ __forceinline__ float tanh_fast(float x) {
  const float xc = fminf(fmaxf(x, -30.f), 30.f);
  const float t = exp2_fast(xc * 2.885390082f);   // 2*log2(e)
  return (t - 1.f) * rcp_fast(t + 1.f);
}
__device__ __forceinline__ float sig5_fast(float o) {
  const float u = exp2_fast((5.f - o) * 1.4426950f);
  return rcp_fast(1.f + u);
}

// leaky-relu + packed f32x4 -> f16x4 (RTZ)
__device__ __forceinline__ half4 leaky_pack(f32x4 a) {
  const float v0 = fmaxf(a[0], a[0] * 0.01f);
  const float v1 = fmaxf(a[1], a[1] * 0.01f);
  const float v2 = fmaxf(a[2], a[2] * 0.01f);
  const float v3 = fmaxf(a[3], a[3] * 0.01f);
  const half2 lo = __builtin_bit_cast(half2, __builtin_amdgcn_cvt_pkrtz(v0, v1));
  const half2 hi = __builtin_bit_cast(half2, __builtin_amdgcn_cvt_pkrtz(v2, v3));
  return __builtin_shufflevector(lo, hi, 0, 1, 2, 3);
}

// ---- workspace layout (bytes), all offsets 256-aligned ----
// Side outputs PLANE-MAJOR: alpha[p][ray], basis[p][ray][8], coeff[pg][24][ray]
#define O_HS     0           // Hs[192][9] f32                     (6912)
#define O_KICAM  7168        // ki[9], cam[3] f32                  (48)
#define O_ALPHA  7424        // alpha[p][ray] f32                  (786432)
#define O_COEFF  793856      // coeff[pg][24][ray] f32             (1572864)
#define O_PW0    2366720     // packed weights, contiguous (see pack_all)
#define O_PW1    2415872
#define O_PW2    2710784
#define O_PW3    3005696
#define O_PW4    3300608
#define O_PWO    3595520
#define O_PBW0   3620096
#define O_PBW1   3624192
#define O_PBWO   3632384
#define O_BASIS  3634432     // basis[p][ray][8] f32               (6291456)
#define WS_NEED  (O_BASIS + 6291456)

// ---------------------------------------------------------------------------
// prep: homographies Hs[p], ki, camera
// ---------------------------------------------------------------------------
__global__ void prep_kernel(const float* __restrict__ ref_rT, const float* __restrict__ ref_t,
                            const float* __restrict__ ref_k, const float* __restrict__ feat_r,
                            const float* __restrict__ feat_t, const float* __restrict__ feat_center,
                            const float* __restrict__ feat_k, const float* __restrict__ planes,
                            float* __restrict__ wsHs, float* __restrict__ wsKiCam)
{
  __shared__ float sKi[9], sHa[9], sHb[9], sHc[1];
  if (threadIdx.x == 0) {
    float a = feat_k[0], b = feat_k[1], c = feat_k[2];
    float d = feat_k[3], e = feat_k[4], f = feat_k[5];
    float g = feat_k[6], h = feat_k[7], i = feat_k[8];
    float A = e * i - f * h, B = -(d * i - f * g), C = d * h - e * g;
    float det = a * A + b * B + c * C;
    float id = 1.0f / det;
    float ki[9];
    ki[0] = A * id;             ki[1] = -(b * i - c * h) * id;  ki[2] = (b * f - c * e) * id;
    ki[3] = B * id;             ki[4] = (a * i - c * g) * id;   ki[5] = -(a * f - c * d) * id;
    ki[6] = C * id;             ki[7] = -(a * h - b * g) * id;  ki[8] = (a * e - b * d) * id;
    float nr[9];
    for (int r2 = 0; r2 < 3; ++r2)
      for (int c2 = 0; c2 < 3; ++c2) {
        float s = 0.f;
        for (int k2 = 0; k2 < 3; ++k2) s += feat_r[r2 * 3 + k2] * ref_rT[k2 * 3 + c2];
        nr[r2 * 3 + c2] = s;
      }
    float ntv[3];
    for (int r2 = 0; r2 < 3; ++r2) {
      float s = 0.f;
      for (int k2 = 0; k2 < 3; ++k2) s += nr[r2 * 3 + k2] * ref_t[k2];
      ntv[r2] = -s + feat_t[r2];
    }
    float Ha[9];
    for (int r2 = 0; r2 < 3; ++r2)
      for (int c2 = 0; c2 < 3; ++c2) Ha[r2 * 3 + c2] = nr[c2 * 3 + r2];  // new_r^T
    float u[3];
    for (int r2 = 0; r2 < 3; ++r2) {
      float s = 0.f;
      for (int k2 = 0; k2 < 3; ++k2) s += Ha[r2 * 3 + k2] * ntv[k2];
      u[r2] = s;
    }
    float Hb[9];
    for (int r2 = 0; r2 < 3; ++r2)
      for (int c2 = 0; c2 < 3; ++c2) Hb[r2 * 3 + c2] = u[r2] * Ha[6 + c2];
    float cam[3];
    for (int r2 = 0; r2 < 3; ++r2) {
      float s = 0.f;
      for (int k2 = 0; k2 < 3; ++k2) s += ref_rT[k2 * 3 + r2] * feat_center[k2];
      cam[r2] = s + ref_t[r2];
    }
    for (int j = 0; j < 9; ++j) { sKi[j] = ki[j]; sHa[j] = Ha[j]; sHb[j] = Hb[j]; }
    sHc[0] = u[2];
    for (int j = 0; j < 9; ++j) wsKiCam[j] = ki[j];
    for (int j = 0; j < 3; ++j) wsKiCam[9 + j] = cam[j];
  }
  __syncthreads();
  int p = threadIdx.x;
  if (p < NPLANES) {
    float dnm = -planes[p] - sHc[0];
    float T[9];
    for (int j = 0; j < 9; ++j) T[j] = sHa[j] + sHb[j] / dnm;
    float U[9];
    for (int r2 = 0; r2 < 3; ++r2)
      for (int c2 = 0; c2 < 3; ++c2) {
        float s = 0.f;
        for (int k2 = 0; k2 < 3; ++k2) s += ref_k[r2 * 3 + k2] * T[k2 * 3 + c2];
        U[r2 * 3 + c2] = s;
      }
    for (int r2 = 0; r2 < 3; ++r2)
      for (int c2 = 0; c2 < 3; ++c2) {
        float s = 0.f;
        for (int k2 = 0; k2 < 3; ++k2) s += U[r2 * 3 + k2] * sKi[k2 * 3 + c2];
        wsHs[p * 9 + r2 * 3 + c2] = s;
      }
  }
}

// ---------------------------------------------------------------------------
// pack_all: every weight matrix -> f16 fragment blocks for 16x16x32.
// dst block (kc,t) holds 512 halves [g(4)][ln(16)][j(8)]:
//   value = W[kc*32 + g*8 + j][t*16 + ln]
// ---------------------------------------------------------------------------
__global__ void pack_all_kernel(const float* __restrict__ w0, const float* __restrict__ w1,
                                const float* __restrict__ w2, const float* __restrict__ w3,
                                const float* __restrict__ w4, const float* __restrict__ wo,
                                const float* __restrict__ bw0, const float* __restrict__ bw1,
                                const float* __restrict__ bwo, _Float16* __restrict__ dst)
{
  const int idx = blockIdx.x * 256 + threadIdx.x;
  const float* src; int Ksrc, Nsrc, NP, l;
  if (idx < 24576)       { src = w0;  Ksrc = 56;  Nsrc = 384; NP = 384; l = idx; }
  else if (idx < 172032) { src = w1;  Ksrc = 384; Nsrc = 384; NP = 384; l = idx - 24576; }
  else if (idx < 319488) { src = w2;  Ksrc = 384; Nsrc = 384; NP = 384; l = idx - 172032; }
  else if (idx < 466944) { src = w3;  Ksrc = 384; Nsrc = 384; NP = 384; l = idx - 319488; }
  else if (idx < 614400) { src = w4;  Ksrc = 384; Nsrc = 384; NP = 384; l = idx - 466944; }
  else if (idx < 626688) { src = wo;  Ksrc = 384; Nsrc = 25;  NP = 32;  l = idx - 614400; }
  else if (idx < 628736) { src = bw0; Ksrc = 12;  Nsrc = 64;  NP = 64;  l = idx - 626688; }
  else if (idx < 632832) { src = bw1; Ksrc = 64;  Nsrc = 64;  NP = 64;  l = idx - 628736; }
  else if (idx < 633856) { src = bwo; Ksrc = 64;  Nsrc = 8;   NP = 16;  l = idx - 632832; }
  else return;
  const int within = l & 511, blk = l >> 9;
  const int kg = within >> 7, ln = (within >> 3) & 15, j = within & 7;
  const int ntiles = NP >> 4;
  const int nt = blk % ntiles, kc = blk / ntiles;
  const int k = kc * 32 + kg * 8 + j, nn = nt * 16 + ln;
  const float v = (k < Ksrc && nn < Nsrc) ? src[k * Nsrc + nn] : 0.0f;
  dst[idx] = (_Float16)v;
}

// ---------------------------------------------------------------------------
// main MLP kernel: 64 points per block (one plane), 256 threads = 4 waves.
// Weights = A (m=feature), activations = B (n=point). 16x16x32 MFMA.
// hbuf fragment-ordered; lane reads B-frag at hb[pt*6144 + kc*512 + lane*8].
// Cross-layer weight prefetch: awp[] holds next layer's kc=0 A-fragments,
// loaded before the epilogue barriers so L2 latency hides under them.
// ---------------------------------------------------------------------------
__device__ __forceinline__ void pre6(half8 awp[6], const _Float16* __restrict__ w,
                                     int wv, int lane) {
  #pragma unroll
  for (int ft = 0; ft < 6; ++ft)
    awp[ft] = *(const half8*)&w[(wv * 6 + ft) * 512 + lane * 8];
}

template <int NKC, bool PRE>
__device__ __forceinline__ void hidden_layer(_Float16* hb, const _Float16* __restrict__ wl,
                                             const _Float16* __restrict__ wlnext,
                                             const float* __restrict__ bias, half8 awp[6],
                                             int wv, int g, int ln, int lane)
{
  f32x4 acc[6][4];   // [feature-tile][point-tile]
  #pragma unroll
  for (int ft = 0; ft < 6; ++ft) {
    const f32x4 bv4 = *(const f32x4*)&bias[(wv * 6 + ft) * 16 + g * 4];
    #pragma unroll
    for (int pt = 0; pt < 4; ++pt) acc[ft][pt] = bv4;
  }
  // kc = 0 uses prefetched weights
  {
    half8 bx[4];
    #pragma unroll
    for (int pt = 0; pt < 4; ++pt)
      bx[pt] = *(const half8*)&hb[pt * 6144 + lane * 8];
    #pragma unroll
    for (int ft = 0; ft < 6; ++ft)
      #pragma unroll
      for (int pt = 0; pt < 4; ++pt)
        acc[ft][pt] = MFMA32(awp[ft], bx[pt], acc[ft][pt]);
  }
  #pragma unroll 2
  for (int kc = 1; kc < NKC; ++kc) {
    half8 aw[6];
    #pragma unroll
    for (int ft = 0; ft < 6; ++ft)
      aw[ft] = *(const half8*)&wl[(kc * 24 + wv * 6 + ft) * 512 + lane * 8];
    half8 bx[4];
    #pragma unroll
    for (int pt = 0; pt < 4; ++pt)
      bx[pt] = *(const half8*)&hb[pt * 6144 + kc * 512 + lane * 8];
    #pragma unroll
    for (int ft = 0; ft < 6; ++ft)
      #pragma unroll
      for (int pt = 0; pt < 4; ++pt)
        acc[ft][pt] = MFMA32(aw[ft], bx[pt], acc[ft][pt]);
  }
  if (PRE) pre6(awp, wlnext, wv, lane);   // in flight across both barriers
  __syncthreads();   // all reads of hb done before overwrite
  #pragma unroll
  for (int pt = 0; pt < 4; ++pt)
    #pragma unroll
    for (int ft = 0; ft < 6; ++ft) {
      const int f0 = wv * 96 + ft * 16 + g * 4;
      *(half4*)&hb[pt * 6144 + (f0 >> 5) * 512 + ((f0 >> 3) & 3) * 128 + ln * 8 + (f0 & 7)] =
          leaky_pack(acc[ft][pt]);
    }
  __syncthreads();
}

// basis layer: no internal barriers (caller manages). Reads cols starting at
// src_kc*32, writes features dstC + wv*16 + g*4 (disjoint LDS region).
template <int NKC>
__device__ __forceinline__ void basis_hidden(_Float16* hb, const _Float16* __restrict__ wl,
                                             const float* __restrict__ bias,
                                             int src_kc, int dstC,
                                             int wv, int g, int ln, int lane)
{
  f32x4 acc[4];      // [point-tile], this wave owns feature-tile wv
  const f32x4 bv4 = *(const f32x4*)&bias[wv * 16 + g * 4];
  #pragma unroll
  for (int pt = 0; pt < 4; ++pt) acc[pt] = bv4;
  #pragma unroll
  for (int kc = 0; kc < NKC; ++kc) {
    half8 aw = *(const half8*)&wl[(kc * 4 + wv) * 512 + lane * 8];
    #pragma unroll
    for (int pt = 0; pt < 4; ++pt) {
      half8 bx = *(const half8*)&hb[pt * 6144 + (src_kc + kc) * 512 + lane * 8];
      acc[pt] = MFMA32(aw, bx, acc[pt]);
    }
  }
  const int f0 = dstC + wv * 16 + g * 4;
  #pragma unroll
  for (int pt = 0; pt < 4; ++pt)
    *(half4*)&hb[pt * 6144 + (f0 >> 5) * 512 + ((f0 >> 3) & 3) * 128 + ln * 8 + (f0 & 7)] =
        leaky_pack(acc[pt]);
}

__global__ __launch_bounds__(256, 3) void mlp_kernel(
    const int* __restrict__ selection, const float* __restrict__ planes,
    const float* __restrict__ wsHs, const float* __restrict__ wsKiCam,
    const _Float16* __restrict__ pw0, const _Float16* __restrict__ pw1,
    const _Float16* __restrict__ pw2, const _Float16* __restrict__ pw3,
    const _Float16* __restrict__ pw4, const _Float16* __restrict__ pwo,
    const float* __restrict__ b0, const float* __restrict__ b1,
    const float* __restrict__ b2, const float* __restrict__ b3,
    const float* __restrict__ b4, const float* __restrict__ bo,
    const _Float16* __restrict__ pbw0, const _Float16* __restrict__ pbw1,
    const _Float16* __restrict__ pbwo,
    const float* __restrict__ bb0, const float* __restrict__ bb1,
    const float* __restrict__ bbo,
    float* __restrict__ wsAlpha, float* __restrict__ wsCoeff, float* __restrict__ wsBasis)
{
  __shared__ _Float16 hbuf[4 * 6144];   // 49152 B, fragment-ordered
  const int t = threadIdx.x;
  const int m0 = blockIdx.x * 64;
  const int p = m0 >> 10;       // plane (blocks never straddle planes: 16 blocks/plane)
  const int r0 = m0 & 1023;
  const int lane = t & 63, wv = t >> 6;
  const int g = lane >> 4, ln = lane & 15;

  half8 awp[6];
  pre6(awp, pw0, wv, lane);     // layer-0 kc=0 weights in flight during encode

  // ---- phase 1: positional encoding -> cols 0..63, AND venc values (regs) ----
  float vencv[4];
  {
    const int i = t >> 2, q = t & 3;   // 4 threads per point
    const int ray = r0 + i;
    const int sel = selection[ray];
    const float cx = (float)(sel % IMW), cy = (float)(sel / IMW);
    const float* H = wsHs + p * 9;
    const float pr0 = H[0] * cx + H[1] * cy + H[2];
    const float pr1 = H[3] * cx + H[4] * cy + H[5];
    const float pr2 = H[6] * cx + H[7] * cy + H[8];
    const float rx = pr0 / pr2, ry = pr1 / pr2;
    const float wx = (rx / 767.0f) * 2.0f - 1.0f;
    const float wy = (ry / 511.0f) * 2.0f - 1.0f;
    const float zc = -1.0f + (float)p * (2.0f / 191.0f);
    // sin(base * pi/2 * 2^c) = sin_rev(base * 2^(c-2)); cos = sin_rev(+0.25)
    #pragma unroll
    for (int cc = 0; cc < 7; ++cc) {
      const int c = q * 7 + cc;
      float base; int e;
      if (c < 10)      { base = wx; e = c; }
      else if (c < 20) { base = wy; e = c - 10; }
      else             { base = zc; e = c - 20; }
      const float rev = ldexpf(base, e - 2);
      hbuf[FR(i, c)]      = (_Float16)sin_rev(rev);
      hbuf[FR(i, c + 28)] = (_Float16)sin_rev(rev + 0.25f);
    }
    hbuf[FR(i, 56 + q)] = (_Float16)0.f;
    hbuf[FR(i, 60 + q)] = (_Float16)0.f;

    // view-direction encoding values (written to LDS later, after output layer)
    const float pd = planes[p];
    const float* ki = wsKiCam; const float* cam = wsKiCam + 9;
    const float c0 = rx * pd, c1 = ry * pd, c2 = pd;
    const float vx0 = ki[0] * c0 + ki[1] * c1 + ki[2] * c2 - cam[0];
    const float vy0 = ki[3] * c0 + ki[4] * c1 + ki[5] * c2 - cam[1];
    const float vz0 = ki[6] * c0 + ki[7] * c1 + ki[8] * c2 - cam[2];
    const float nrm = sqrtf(vx0 * vx0 + vy0 * vy0 + vz0 * vz0) + 1e-7f;
    const float vx = vx0 / nrm, vy = vy0 / nrm;
    #pragma unroll
    for (int cc = 0; cc < 4; ++cc) {
      const int c = q * 4 + cc;
      float v;
      if (c < 6) {
        v = sin_rev(ldexpf((c < 3) ? vx : vy, (c % 3) - 2));
      } else if (c < 12) {
        const int c6 = c - 6;
        v = sin_rev(ldexpf((c6 < 3) ? vx : vy, (c6 % 3) - 2) + 0.25f);
      } else v = 0.f;
      vencv[cc] = v;
    }
  }
  __syncthreads();

  // ---- main MLP (each layer prefetches the next layer's kc=0 weights) ----
  hidden_layer<2,  true >(hbuf, pw0, pw1, b0, awp, wv, g, ln, lane);
  hidden_layer<12, true >(hbuf, pw1, pw2, b1, awp, wv, g, ln, lane);
  hidden_layer<12, true >(hbuf, pw2, pw3, b2, awp, wv, g, ln, lane);
  hidden_layer<12, true >(hbuf, pw3, pw4, b3, awp, wv, g, ln, lane);
  hidden_layer<12, false>(hbuf, pw4, pw4, b4, awp, wv, g, ln, lane);

  // ---- output layer (25 features padded to 32 = 2 ft-tiles), wave owns pt=wv ----
  f32x4 acc2[2];
  {
    #pragma unroll
    for (int ft = 0; ft < 2; ++ft) {
      f32x4 bv;
      #pragma unroll
      for (int r = 0; r < 4; ++r) {
        const int f = ft * 16 + g * 4 + r;
        bv[r] = (f < 25) ? bo[f] : 0.f;
      }
      acc2[ft] = bv;
    }
    #pragma unroll 2
    for (int kc = 0; kc < 12; ++kc) {
      half8 bx = *(const half8*)&hbuf[wv * 6144 + kc * 512 + lane * 8];
      #pragma unroll
      for (int ft = 0; ft < 2; ++ft) {
        half8 aw = *(const half8*)&pwo[(kc * 2 + ft) * 512 + lane * 8];
        acc2[ft] = MFMA32(aw, bx, acc2[ft]);
      }
    }
    __syncthreads();   // all hbuf reads done
  }

  // ---- write venc (from regs) -> cols 0..15 ----
  {
    const int i = t >> 2, q = t & 3;
    #pragma unroll
    for (int cc = 0; cc < 4; ++cc)
      hbuf[FR(i, q * 4 + cc)] = (_Float16)vencv[cc];
  }
  __syncthreads();   // venc visible to all waves

  // ---- alpha / coeff epilogue from output-layer registers (plane-major) ----
  // (global stores overlap with basis MFMA below — no barrier between)
  {
    if (g == 0) {   // feature 0 lives in reg r=0 of g=0, ft=0
      const int ray = r0 + wv * 16 + ln;
      wsAlpha[p * RAYS + ray] = sig5_fast(acc2[0][0]);
    }
    if ((p % 12) == 0) {
      const int pg = p / 12;
      const int ray = r0 + wv * 16 + ln;
      #pragma unroll
      for (int ft = 0; ft < 2; ++ft)
        #pragma unroll
        for (int r = 0; r < 4; ++r) {
          const int f = ft * 16 + g * 4 + r;
          if (f >= 1 && f < 25)
            wsCoeff[(pg * 24 + (f - 1)) * RAYS + ray] = tanh_fast(acc2[ft][r]);
        }
    }
  }

  // ---- basis MLP: venc(cols0-31) -> cols64-127 -> cols128-191 -> out ----
  basis_hidden<1>(hbuf, pbw0, bb0, 0, 64, wv, g, ln, lane);
  __syncthreads();
  basis_hidden<2>(hbuf, pbw1, bb1, 2, 128, wv, g, ln, lane);
  __syncthreads();
  {
    f32x4 accO = (f32x4){0.f, 0.f, 0.f, 0.f};
    #pragma unroll
    for (int kc = 0; kc < 2; ++kc) {
      half8 aw = *(const half8*)&pbwo[kc * 512 + lane * 8];
      half8 bx = *(const half8*)&hbuf[wv * 6144 + (4 + kc) * 512 + lane * 8];
      accO = MFMA32(aw, bx, accO);
    }
    if (g < 2) {   // features 0..7; one float4 store per lane, 512B/wave span
      const int ray = r0 + wv * 16 + ln;
      f32x4 bv;
      #pragma unroll
      for (int r = 0; r < 4; ++r)
        bv[r] = tanh_fast(accO[r] + bbo[g * 4 + r]);
      *(f32x4*)&wsBasis[(p * RAYS + ray) * 8 + g * 4] = bv;
    }
  }
}

// ---------------------------------------------------------------------------
// composite: per ray (block, 192 threads = 1 thread/plane):
// grid-sample sigmoid(mpi), illum = coeff . basis, clip, prefix-product scan,
// weighted sum -> out[3][1024]
// ---------------------------------------------------------------------------
__global__ __launch_bounds__(192) void composite_kernel(
    const float* __restrict__ mpi, const int* __restrict__ selection,
    const float* __restrict__ wsHs, const float* __restrict__ wsAlpha,
    const float* __restrict__ wsCoeff, const float* __restrict__ wsBasis,
    float* __restrict__ out)
{
  const int ray = blockIdx.x;
  const int p = threadIdx.x;
  const int sel = selection[ray];
  const float cx = (float)(sel % IMW), cy = (float)(sel / IMW);
  const float* H = wsHs + p * 9;
  const float pr0 = H[0] * cx + H[1] * cy + H[2];
  const float pr1 = H[3] * cx + H[4] * cy + H[5];
  const float pr2 = H[6] * cx + H[7] * cy + H[8];
  const float rx = pr0 / pr2, ry = pr1 / pr2;
  const float wx = (rx / 767.0f) * 2.0f - 1.0f;
  const float wy = (ry / 511.0f) * 2.0f - 1.0f;
  const float x = (wx + 1.0f) * 0.5f * 767.0f;
  const float y = (wy + 1.0f) * 0.5f * 511.0f;
  const float gz = -1.0f + (float)(p / 12) * (2.0f / 15.0f);
  const float z = (gz + 1.0f) * 0.5f * 15.0f;
  const float x0 = floorf(x), y0 = floorf(y), z0 = floorf(z);
  float rgb0 = 0.f, rgb1 = 0.f, rgb2 = 0.f;
  #pragma unroll
  for (int dz = 0; dz < 2; ++dz)
    #pragma unroll
    for (int dy = 0; dy < 2; ++dy)
      #pragma unroll
      for (int dx = 0; dx < 2; ++dx) {
        const float xi = x0 + (float)dx, yi = y0 + (float)dy, zi = z0 + (float)dz;
        const float w = (1.f - fabsf(x - xi)) * (1.f - fabsf(y - yi)) * (1.f - fabsf(z - zi));
        const bool valid = (xi >= 0.f) && (xi < 768.f) && (yi >= 0.f) && (yi < 512.f)
                        && (zi >= 0.f) && (zi < 16.f);
        if (valid && w != 0.f) {
          const int ix = (int)xi, iy = (int)yi, iz = (int)zi;
          const int base = iz * 3 * (IMW * IMH) + iy * IMW + ix;   // mpi[d][c][y][x]
          const float v0 = mpi[base];
          const float v1 = mpi[base + IMW * IMH];
          const float v2 = mpi[base + 2 * IMW * IMH];
          rgb0 += w * (1.f / (1.f + expf(-v0)));
          rgb1 += w * (1.f / (1.f + expf(-v1)));
          rgb2 += w * (1.f / (1.f + expf(-v2)));
        }
      }
  const float* bs = wsBasis + (p * RAYS + ray) * 8;
  const float* cf = wsCoeff + (p / 12) * 24 * RAYS + ray;
  float il0 = 0.f, il1 = 0.f, il2 = 0.f;
  #pragma unroll
  for (int j = 0; j < 8; ++j) {
    const float bj = bs[j];
    il0 += cf[j * RAYS] * bj;
    il1 += cf[(8 + j) * RAYS] * bj;
    il2 += cf[(16 + j) * RAYS] * bj;
  }
  rgb0 = fminf(fmaxf(rgb0 + il0, 0.f), 1.f);
  rgb1 = fminf(fmaxf(rgb1 + il1, 0.f), 1.f);
  rgb2 = fminf(fmaxf(rgb2 + il2, 0.f), 1.f);
  const float a = wsAlpha[p * RAYS + ray];
  const int lane = p & 63, w64 = p >> 6;
  // inclusive prefix product of (1-a) within each wave
  float xs = 1.f - a;
  #pragma unroll
  for (int off = 1; off < 64; off <<= 1) {
    const float v = __shfl_up(xs, off, 64);
    if (lane >= off) xs *= v;
  }
  __shared__ float wtot[3];
  __shared__ float part[3][3];
  if (lane == 63) wtot[w64] = xs;
  __syncthreads();
  float pre = 1.f;
  #pragma unroll
  for (int q = 0; q < 2; ++q)
    if (q < w64) pre *= wtot[q];
  float excl = __shfl_up(xs, 1, 64);
  if (lane == 0) excl = 1.f;
  const float wa = pre * excl * a;
  float s0 = wa * rgb0, s1 = wa * rgb1, s2 = wa * rgb2;
  #pragma unroll
  for (int off = 32; off >= 1; off >>= 1) {
    s0 += __shfl_down(s0, off, 64);
    s1 += __shfl_down(s1, off, 64);
    s2 += __shfl_down(s2, off, 64);
  }
  if (lane == 0) { part[w64][0] = s0; part[w64][1] = s1; part[w64][2] = s2; }
  __syncthreads();
  if (p == 0) {
    out[0 * RAYS + ray] = part[0][0] + part[1][0] + part[2][0];
    out[1 * RAYS + ray] = part[0][1] + part[1][1] + part[2][1];
    out[2 * RAYS + ray] = part[0][2] + part[1][2] + part[2][2];
  }
}

// ---------------------------------------------------------------------------
extern "C" void kernel_launch(void* const* d_in, const int* in_sizes, int n_in,
                              void* d_out, int out_size, void* d_ws, size_t ws_size,
                              hipStream_t stream)
{
  (void)in_sizes; (void)n_in; (void)out_size;
  const float* mpi    = (const float*)d_in[0];
  const float* w0     = (const float*)d_in[1];
  const float* b0     = (const float*)d_in[2];
  const float* w1     = (const float*)d_in[3];
  const float* b1     = (const float*)d_in[4];
  const float* w2     = (const float*)d_in[5];
  const float* b2     = (const float*)d_in[6];
  const float* w3     = (const float*)d_in[7];
  const float* b3     = (const float*)d_in[8];
  const float* w4     = (const float*)d_in[9];
  const float* b4     = (const float*)d_in[10];
  const float* wo     = (const float*)d_in[11];
  const float* bo     = (const float*)d_in[12];
  const float* bw0    = (const float*)d_in[13];
  const float* bb0    = (const float*)d_in[14];
  const float* bw1    = (const float*)d_in[15];
  const float* bb1    = (const float*)d_in[16];
  const float* bwo    = (const float*)d_in[17];
  const float* bbo    = (const float*)d_in[18];
  const float* ref_rT = (const float*)d_in[19];
  const float* ref_t  = (const float*)d_in[20];
  const float* ref_k  = (const float*)d_in[21];
  const float* feat_r = (const float*)d_in[22];
  const float* feat_t = (const float*)d_in[23];
  const float* feat_c = (const float*)d_in[24];
  const float* feat_k = (const float*)d_in[25];
  const float* planes = (const float*)d_in[26];
  const int*   selection = (const int*)d_in[27];
  float* outp = (float*)d_out;
  char* ws = (char*)d_ws;
  if (ws_size < (size_t)WS_NEED) return;   // workspace too small -> visible failure

  float* wsHs    = (float*)(ws + O_HS);
  float* wsKiCam = (float*)(ws + O_KICAM);
  float* wsAlpha = (float*)(ws + O_ALPHA);
  float* wsCoeff = (float*)(ws + O_COEFF);
  float* wsBasis = (float*)(ws + O_BASIS);
  _Float16* pw0  = (_Float16*)(ws + O_PW0);
  _Float16* pw1  = (_Float16*)(ws + O_PW1);
  _Float16* pw2  = (_Float16*)(ws + O_PW2);
  _Float16* pw3  = (_Float16*)(ws + O_PW3);
  _Float16* pw4  = (_Float16*)(ws + O_PW4);
  _Float16* pwo  = (_Float16*)(ws + O_PWO);
  _Float16* pbw0 = (_Float16*)(ws + O_PBW0);
  _Float16* pbw1 = (_Float16*)(ws + O_PBW1);
  _Float16* pbwo = (_Float16*)(ws + O_PBWO);

  prep_kernel<<<1, 256, 0, stream>>>(ref_rT, ref_t, ref_k, feat_r, feat_t, feat_c,
                                     feat_k, planes, wsHs, wsKiCam);
  pack_all_kernel<<<2476, 256, 0, stream>>>(w0, w1, w2, w3, w4, wo, bw0, bw1, bwo, pw0);

  mlp_kernel<<<(NPLANES * RAYS) / 64, 256, 0, stream>>>(
      selection, planes, wsHs, wsKiCam,
      pw0, pw1, pw2, pw3, pw4, pwo,
      b0, b1, b2, b3, b4, bo,
      pbw0, pbw1, pbwo, bb0, bb1, bbo,
      wsAlpha, wsCoeff, wsBasis);

  composite_kernel<<<RAYS, NPLANES, 0, stream>>>(mpi, selection, wsHs, wsAlpha,
                                                 wsCoeff, wsBasis, outp);
}

// Round 11
// 311.693 us; speedup vs baseline: 1.3134x; 1.3134x over previous
//
#include <hip/hip_runtime.h>
#include <hip/hip_bf16.h>
#include <math.h>

// ---------------------------------------------------------------------------
// MPI-NeRF style network renderer for MI355X (gfx950).
// R10: R7 hidden-layer body restored (R9's awp[6] prefetch array escaped to
//      scratch -> 660MB traffic). Kept: venc precomputed in phase 1 (regs,
//      static idx), basis-MLP ping-pong via disjoint LDS regions (3 barriers
//      fewer in tail). Everything else identical to R7 (263us).
// ---------------------------------------------------------------------------

typedef _Float16 half2 __attribute__((ext_vector_type(2)));
typedef _Float16 half4 __attribute__((ext_vector_type(4)));
typedef _Float16 half8 __attribute__((ext_vector_type(8)));
typedef float f32x4 __attribute__((ext_vector_type(4)));

#if __has_builtin(__builtin_amdgcn_mfma_f32_16x16x32_f16)
#define MFMA32(a, b, c) __builtin_amdgcn_mfma_f32_16x16x32_f16((a), (b), (c), 0, 0, 0)
#else
#define MFMA32(a, b, c) (c)   // host-pass placeholder (never executed)
#endif

#define NPLANES 192
#define RAYS    1024
#define IMW     768
#define IMH     512

// fragment-order index into hbuf: point i (0..63), feature/column c (0..383)
// layout [pt(4)][kc(12)][g(4)][ln(16)][j(8)], strides 6144/512/128/8/1 halves
#define FR(i, c) ((((i) >> 4) * 6144) + (((c) >> 5) * 512) + ((((c) >> 3) & 3) * 128) \
                  + (((i) & 15) * 8) + ((c) & 7))

// sin(2*pi*rev) via HW: fract to [0,1) then v_sin
__device__ __forceinline__ float sin_rev(float rev) {
  float f, r;
  asm("v_fract_f32 %0, %1" : "=v"(f) : "v"(rev));
  asm("v_sin_f32 %0, %1" : "=v"(r) : "v"(f));
  return r;
}
__device__ __forceinline__ float exp2_fast(float x) {
  float r;
  asm("v_exp_f32 %0, %1" : "=v"(r) : "v"(x));
  return r;
}
__device__ __forceinline__ float rcp_fast(float x) {
  float r;
  asm("v_rcp_f32 %0, %1" : "=v"(r) : "v"(x));
  return r;
}
__device__ __forceinline__ float tanh_fast(float x) {
  const float xc = fminf(fmaxf(x, -30.f), 30.f);
  const float t = exp2_fast(xc * 2.885390082f);   // 2*log2(e)
  return (t - 1.f) * rcp_fast(t + 1.f);
}
__device__ __forceinline__ float sig5_fast(float o) {
  const float u = exp2_fast((5.f - o) * 1.4426950f);
  return rcp_fast(1.f + u);
}

// leaky-relu + packed f32x4 -> f16x4 (RTZ)
__device__ __forceinline__ half4 leaky_pack(f32x4 a) {
  const float v0 = fmaxf(a[0], a[0] * 0.01f);
  const float v1 = fmaxf(a[1], a[1] * 0.01f);
  const float v2 = fmaxf(a[2], a[2] * 0.01f);
  const float v3 = fmaxf(a[3], a[3] * 0.01f);
  const half2 lo = __builtin_bit_cast(half2, __builtin_amdgcn_cvt_pkrtz(v0, v1));
  const half2 hi = __builtin_bit_cast(half2, __builtin_amdgcn_cvt_pkrtz(v2, v3));
  return __builtin_shufflevector(lo, hi, 0, 1, 2, 3);
}

// ---- workspace layout (bytes), all offsets 256-aligned ----
// Side outputs PLANE-MAJOR: alpha[p][ray], basis[p][ray][8], coeff[pg][24][ray]
#define O_HS     0           // Hs[192][9] f32                     (6912)
#define O_KICAM  7168        // ki[9], cam[3] f32                  (48)
#define O_ALPHA  7424        // alpha[p][ray] f32                  (786432)
#define O_COEFF  793856      // coeff[pg][24][ray] f32             (1572864)
#define O_PW0    2366720     // packed weights, contiguous (see pack_all)
#define O_PW1    2415872
#define O_PW2    2710784
#define O_PW3    3005696
#define O_PW4    3300608
#define O_PWO    3595520
#define O_PBW0   3620096
#define O_PBW1   3624192
#define O_PBWO   3632384
#define O_BASIS  3634432     // basis[p][ray][8] f32               (6291456)
#define WS_NEED  (O_BASIS + 6291456)

// ---------------------------------------------------------------------------
// prep: homographies Hs[p], ki, camera
// ---------------------------------------------------------------------------
__global__ void prep_kernel(const float* __restrict__ ref_rT, const float* __restrict__ ref_t,
                            const float* __restrict__ ref_k, const float* __restrict__ feat_r,
                            const float* __restrict__ feat_t, const float* __restrict__ feat_center,
                            const float* __restrict__ feat_k, const float* __restrict__ planes,
                            float* __restrict__ wsHs, float* __restrict__ wsKiCam)
{
  __shared__ float sKi[9], sHa[9], sHb[9], sHc[1];
  if (threadIdx.x == 0) {
    float a = feat_k[0], b = feat_k[1], c = feat_k[2];
    float d = feat_k[3], e = feat_k[4], f = feat_k[5];
    float g = feat_k[6], h = feat_k[7], i = feat_k[8];
    float A = e * i - f * h, B = -(d * i - f * g), C = d * h - e * g;
    float det = a * A + b * B + c * C;
    float id = 1.0f / det;
    float ki[9];
    ki[0] = A * id;             ki[1] = -(b * i - c * h) * id;  ki[2] = (b * f - c * e) * id;
    ki[3] = B * id;             ki[4] = (a * i - c * g) * id;   ki[5] = -(a * f - c * d) * id;
    ki[6] = C * id;             ki[7] = -(a * h - b * g) * id;  ki[8] = (a * e - b * d) * id;
    float nr[9];
    for (int r2 = 0; r2 < 3; ++r2)
      for (int c2 = 0; c2 < 3; ++c2) {
        float s = 0.f;
        for (int k2 = 0; k2 < 3; ++k2) s += feat_r[r2 * 3 + k2] * ref_rT[k2 * 3 + c2];
        nr[r2 * 3 + c2] = s;
      }
    float ntv[3];
    for (int r2 = 0; r2 < 3; ++r2) {
      float s = 0.f;
      for (int k2 = 0; k2 < 3; ++k2) s += nr[r2 * 3 + k2] * ref_t[k2];
      ntv[r2] = -s + feat_t[r2];
    }
    float Ha[9];
    for (int r2 = 0; r2 < 3; ++r2)
      for (int c2 = 0; c2 < 3; ++c2) Ha[r2 * 3 + c2] = nr[c2 * 3 + r2];  // new_r^T
    float u[3];
    for (int r2 = 0; r2 < 3; ++r2) {
      float s = 0.f;
      for (int k2 = 0; k2 < 3; ++k2) s += Ha[r2 * 3 + k2] * ntv[k2];
      u[r2] = s;
    }
    float Hb[9];
    for (int r2 = 0; r2 < 3; ++r2)
      for (int c2 = 0; c2 < 3; ++c2) Hb[r2 * 3 + c2] = u[r2] * Ha[6 + c2];
    float cam[3];
    for (int r2 = 0; r2 < 3; ++r2) {
      float s = 0.f;
      for (int k2 = 0; k2 < 3; ++k2) s += ref_rT[k2 * 3 + r2] * feat_center[k2];
      cam[r2] = s + ref_t[r2];
    }
    for (int j = 0; j < 9; ++j) { sKi[j] = ki[j]; sHa[j] = Ha[j]; sHb[j] = Hb[j]; }
    sHc[0] = u[2];
    for (int j = 0; j < 9; ++j) wsKiCam[j] = ki[j];
    for (int j = 0; j < 3; ++j) wsKiCam[9 + j] = cam[j];
  }
  __syncthreads();
  int p = threadIdx.x;
  if (p < NPLANES) {
    float dnm = -planes[p] - sHc[0];
    float T[9];
    for (int j = 0; j < 9; ++j) T[j] = sHa[j] + sHb[j] / dnm;
    float U[9];
    for (int r2 = 0; r2 < 3; ++r2)
      for (int c2 = 0; c2 < 3; ++c2) {
        float s = 0.f;
        for (int k2 = 0; k2 < 3; ++k2) s += ref_k[r2 * 3 + k2] * T[k2 * 3 + c2];
        U[r2 * 3 + c2] = s;
      }
    for (int r2 = 0; r2 < 3; ++r2)
      for (int c2 = 0; c2 < 3; ++c2) {
        float s = 0.f;
        for (int k2 = 0; k2 < 3; ++k2) s += U[r2 * 3 + k2] * sKi[k2 * 3 + c2];
        wsHs[p * 9 + r2 * 3 + c2] = s;
      }
  }
}

// ---------------------------------------------------------------------------
// pack_all: every weight matrix -> f16 fragment blocks for 16x16x32.
// dst block (kc,t) holds 512 halves [g(4)][ln(16)][j(8)]:
//   value = W[kc*32 + g*8 + j][t*16 + ln]
// ---------------------------------------------------------------------------
__global__ void pack_all_kernel(const float* __restrict__ w0, const float* __restrict__ w1,
                                const float* __restrict__ w2, const float* __restrict__ w3,
                                const float* __restrict__ w4, const float* __restrict__ wo,
                                const float* __restrict__ bw0, const float* __restrict__ bw1,
                                const float* __restrict__ bwo, _Float16* __restrict__ dst)
{
  const int idx = blockIdx.x * 256 + threadIdx.x;
  const float* src; int Ksrc, Nsrc, NP, l;
  if (idx < 24576)       { src = w0;  Ksrc = 56;  Nsrc = 384; NP = 384; l = idx; }
  else if (idx < 172032) { src = w1;  Ksrc = 384; Nsrc = 384; NP = 384; l = idx - 24576; }
  else if (idx < 319488) { src = w2;  Ksrc = 384; Nsrc = 384; NP = 384; l = idx - 172032; }
  else if (idx < 466944) { src = w3;  Ksrc = 384; Nsrc = 384; NP = 384; l = idx - 319488; }
  else if (idx < 614400) { src = w4;  Ksrc = 384; Nsrc = 384; NP = 384; l = idx - 466944; }
  else if (idx < 626688) { src = wo;  Ksrc = 384; Nsrc = 25;  NP = 32;  l = idx - 614400; }
  else if (idx < 628736) { src = bw0; Ksrc = 12;  Nsrc = 64;  NP = 64;  l = idx - 626688; }
  else if (idx < 632832) { src = bw1; Ksrc = 64;  Nsrc = 64;  NP = 64;  l = idx - 628736; }
  else if (idx < 633856) { src = bwo; Ksrc = 64;  Nsrc = 8;   NP = 16;  l = idx - 632832; }
  else return;
  const int within = l & 511, blk = l >> 9;
  const int kg = within >> 7, ln = (within >> 3) & 15, j = within & 7;
  const int ntiles = NP >> 4;
  const int nt = blk % ntiles, kc = blk / ntiles;
  const int k = kc * 32 + kg * 8 + j, nn = nt * 16 + ln;
  const float v = (k < Ksrc && nn < Nsrc) ? src[k * Nsrc + nn] : 0.0f;
  dst[idx] = (_Float16)v;
}

// ---------------------------------------------------------------------------
// main MLP kernel: 64 points per block (one plane), 256 threads = 4 waves.
// Weights = A (m=feature), activations = B (n=point). 16x16x32 MFMA.
// hbuf fragment-ordered; lane reads B-frag at hb[pt*6144 + kc*512 + lane*8].
// ---------------------------------------------------------------------------
template <int NKC>
__device__ __forceinline__ void hidden_layer(_Float16* hb, const _Float16* __restrict__ wl,
                                             const float* __restrict__ bias,
                                             int wv, int g, int ln, int lane)
{
  f32x4 acc[6][4];   // [feature-tile][point-tile]
  #pragma unroll
  for (int ft = 0; ft < 6; ++ft) {
    const f32x4 bv4 = *(const f32x4*)&bias[(wv * 6 + ft) * 16 + g * 4];
    #pragma unroll
    for (int pt = 0; pt < 4; ++pt) acc[ft][pt] = bv4;
  }
  #pragma unroll 2
  for (int kc = 0; kc < NKC; ++kc) {
    half8 aw[6];
    #pragma unroll
    for (int ft = 0; ft < 6; ++ft)
      aw[ft] = *(const half8*)&wl[(kc * 24 + wv * 6 + ft) * 512 + lane * 8];
    half8 bx[4];
    #pragma unroll
    for (int pt = 0; pt < 4; ++pt)
      bx[pt] = *(const half8*)&hb[pt * 6144 + kc * 512 + lane * 8];
    #pragma unroll
    for (int ft = 0; ft < 6; ++ft)
      #pragma unroll
      for (int pt = 0; pt < 4; ++pt)
        acc[ft][pt] = MFMA32(aw[ft], bx[pt], acc[ft][pt]);
  }
  __syncthreads();   // all reads of hb done before overwrite
  #pragma unroll
  for (int pt = 0; pt < 4; ++pt)
    #pragma unroll
    for (int ft = 0; ft < 6; ++ft) {
      const int f0 = wv * 96 + ft * 16 + g * 4;
      *(half4*)&hb[pt * 6144 + (f0 >> 5) * 512 + ((f0 >> 3) & 3) * 128 + ln * 8 + (f0 & 7)] =
          leaky_pack(acc[ft][pt]);
    }
  __syncthreads();
}

// basis layer: no internal barriers (caller manages). Reads cols starting at
// src_kc*32, writes features dstC + wv*16 + g*4 (disjoint LDS region).
template <int NKC>
__device__ __forceinline__ void basis_hidden(_Float16* hb, const _Float16* __restrict__ wl,
                                             const float* __restrict__ bias,
                                             int src_kc, int dstC,
                                             int wv, int g, int ln, int lane)
{
  f32x4 acc[4];      // [point-tile], this wave owns feature-tile wv
  const f32x4 bv4 = *(const f32x4*)&bias[wv * 16 + g * 4];
  #pragma unroll
  for (int pt = 0; pt < 4; ++pt) acc[pt] = bv4;
  #pragma unroll
  for (int kc = 0; kc < NKC; ++kc) {
    half8 aw = *(const half8*)&wl[(kc * 4 + wv) * 512 + lane * 8];
    #pragma unroll
    for (int pt = 0; pt < 4; ++pt) {
      half8 bx = *(const half8*)&hb[pt * 6144 + (src_kc + kc) * 512 + lane * 8];
      acc[pt] = MFMA32(aw, bx, acc[pt]);
    }
  }
  const int f0 = dstC + wv * 16 + g * 4;
  #pragma unroll
  for (int pt = 0; pt < 4; ++pt)
    *(half4*)&hb[pt * 6144 + (f0 >> 5) * 512 + ((f0 >> 3) & 3) * 128 + ln * 8 + (f0 & 7)] =
        leaky_pack(acc[pt]);
}

__global__ __launch_bounds__(256, 3) void mlp_kernel(
    const int* __restrict__ selection, const float* __restrict__ planes,
    const float* __restrict__ wsHs, const float* __restrict__ wsKiCam,
    const _Float16* __restrict__ pw0, const _Float16* __restrict__ pw1,
    const _Float16* __restrict__ pw2, const _Float16* __restrict__ pw3,
    const _Float16* __restrict__ pw4, const _Float16* __restrict__ pwo,
    const float* __restrict__ b0, const float* __restrict__ b1,
    const float* __restrict__ b2, const float* __restrict__ b3,
    const float* __restrict__ b4, const float* __restrict__ bo,
    const _Float16* __restrict__ pbw0, const _Float16* __restrict__ pbw1,
    const _Float16* __restrict__ pbwo,
    const float* __restrict__ bb0, const float* __restrict__ bb1,
    const float* __restrict__ bbo,
    float* __restrict__ wsAlpha, float* __restrict__ wsCoeff, float* __restrict__ wsBasis)
{
  __shared__ _Float16 hbuf[4 * 6144];   // 49152 B, fragment-ordered
  const int t = threadIdx.x;
  const int m0 = blockIdx.x * 64;
  const int p = m0 >> 10;       // plane (blocks never straddle planes: 16 blocks/plane)
  const int r0 = m0 & 1023;
  const int lane = t & 63, wv = t >> 6;
  const int g = lane >> 4, ln = lane & 15;

  // ---- phase 1: positional encoding -> cols 0..63, AND venc values (regs) ----
  float venc0, venc1, venc2, venc3;
  {
    const int i = t >> 2, q = t & 3;   // 4 threads per point
    const int ray = r0 + i;
    const int sel = selection[ray];
    const float cx = (float)(sel % IMW), cy = (float)(sel / IMW);
    const float* H = wsHs + p * 9;
    const float pr0 = H[0] * cx + H[1] * cy + H[2];
    const float pr1 = H[3] * cx + H[4] * cy + H[5];
    const float pr2 = H[6] * cx + H[7] * cy + H[8];
    const float rx = pr0 / pr2, ry = pr1 / pr2;
    const float wx = (rx / 767.0f) * 2.0f - 1.0f;
    const float wy = (ry / 511.0f) * 2.0f - 1.0f;
    const float zc = -1.0f + (float)p * (2.0f / 191.0f);
    // sin(base * pi/2 * 2^c) = sin_rev(base * 2^(c-2)); cos = sin_rev(+0.25)
    #pragma unroll
    for (int cc = 0; cc < 7; ++cc) {
      const int c = q * 7 + cc;
      float base; int e;
      if (c < 10)      { base = wx; e = c; }
      else if (c < 20) { base = wy; e = c - 10; }
      else             { base = zc; e = c - 20; }
      const float rev = ldexpf(base, e - 2);
      hbuf[FR(i, c)]      = (_Float16)sin_rev(rev);
      hbuf[FR(i, c + 28)] = (_Float16)sin_rev(rev + 0.25f);
    }
    hbuf[FR(i, 56 + q)] = (_Float16)0.f;
    hbuf[FR(i, 60 + q)] = (_Float16)0.f;

    // view-direction encoding values (written to LDS after the output layer)
    const float pd = planes[p];
    const float* ki = wsKiCam; const float* cam = wsKiCam + 9;
    const float c0 = rx * pd, c1 = ry * pd, c2 = pd;
    const float vx0 = ki[0] * c0 + ki[1] * c1 + ki[2] * c2 - cam[0];
    const float vy0 = ki[3] * c0 + ki[4] * c1 + ki[5] * c2 - cam[1];
    const float vz0 = ki[6] * c0 + ki[7] * c1 + ki[8] * c2 - cam[2];
    const float nrm = sqrtf(vx0 * vx0 + vy0 * vy0 + vz0 * vz0) + 1e-7f;
    const float vx = vx0 / nrm, vy = vy0 / nrm;
    const int c0i = q * 4;
    // c = q*4 + cc; cc = 0..3. Compute each explicitly (static storage).
    {
      const int c = c0i + 0;
      venc0 = (c < 6) ? sin_rev(ldexpf((c < 3) ? vx : vy, (c % 3) - 2))
            : (c < 12) ? sin_rev(ldexpf(((c - 6) < 3) ? vx : vy, ((c - 6) % 3) - 2) + 0.25f) : 0.f;
    }
    {
      const int c = c0i + 1;
      venc1 = (c < 6) ? sin_rev(ldexpf((c < 3) ? vx : vy, (c % 3) - 2))
            : (c < 12) ? sin_rev(ldexpf(((c - 6) < 3) ? vx : vy, ((c - 6) % 3) - 2) + 0.25f) : 0.f;
    }
    {
      const int c = c0i + 2;
      venc2 = (c < 6) ? sin_rev(ldexpf((c < 3) ? vx : vy, (c % 3) - 2))
            : (c < 12) ? sin_rev(ldexpf(((c - 6) < 3) ? vx : vy, ((c - 6) % 3) - 2) + 0.25f) : 0.f;
    }
    {
      const int c = c0i + 3;
      venc3 = (c < 6) ? sin_rev(ldexpf((c < 3) ? vx : vy, (c % 3) - 2))
            : (c < 12) ? sin_rev(ldexpf(((c - 6) < 3) ? vx : vy, ((c - 6) % 3) - 2) + 0.25f) : 0.f;
    }
  }
  __syncthreads();

  // ---- main MLP ----
  hidden_layer<2>(hbuf, pw0, b0, wv, g, ln, lane);
  hidden_layer<12>(hbuf, pw1, b1, wv, g, ln, lane);
  hidden_layer<12>(hbuf, pw2, b2, wv, g, ln, lane);
  hidden_layer<12>(hbuf, pw3, b3, wv, g, ln, lane);
  hidden_layer<12>(hbuf, pw4, b4, wv, g, ln, lane);

  // ---- output layer (25 features padded to 32 = 2 ft-tiles), wave owns pt=wv ----
  f32x4 acc2[2];
  {
    #pragma unroll
    for (int ft = 0; ft < 2; ++ft) {
      f32x4 bv;
      #pragma unroll
      for (int r = 0; r < 4; ++r) {
        const int f = ft * 16 + g * 4 + r;
        bv[r] = (f < 25) ? bo[f] : 0.f;
      }
      acc2[ft] = bv;
    }
    #pragma unroll 2
    for (int kc = 0; kc < 12; ++kc) {
      half8 bx = *(const half8*)&hbuf[wv * 6144 + kc * 512 + lane * 8];
      #pragma unroll
      for (int ft = 0; ft < 2; ++ft) {
        half8 aw = *(const half8*)&pwo[(kc * 2 + ft) * 512 + lane * 8];
        acc2[ft] = MFMA32(aw, bx, acc2[ft]);
      }
    }
    __syncthreads();   // all hbuf reads done
  }

  // ---- write venc (from regs) -> cols 0..15 ----
  {
    const int i = t >> 2, q = t & 3;
    hbuf[FR(i, q * 4 + 0)] = (_Float16)venc0;
    hbuf[FR(i, q * 4 + 1)] = (_Float16)venc1;
    hbuf[FR(i, q * 4 + 2)] = (_Float16)venc2;
    hbuf[FR(i, q * 4 + 3)] = (_Float16)venc3;
  }
  __syncthreads();   // venc visible to all waves

  // ---- alpha / coeff epilogue from output-layer registers (plane-major) ----
  // (global stores overlap with basis MFMA below — no barrier between)
  {
    if (g == 0) {   // feature 0 lives in reg r=0 of g=0, ft=0
      const int ray = r0 + wv * 16 + ln;
      wsAlpha[p * RAYS + ray] = sig5_fast(acc2[0][0]);
    }
    if ((p % 12) == 0) {
      const int pg = p / 12;
      const int ray = r0 + wv * 16 + ln;
      #pragma unroll
      for (int ft = 0; ft < 2; ++ft)
        #pragma unroll
        for (int r = 0; r < 4; ++r) {
          const int f = ft * 16 + g * 4 + r;
          if (f >= 1 && f < 25)
            wsCoeff[(pg * 24 + (f - 1)) * RAYS + ray] = tanh_fast(acc2[ft][r]);
        }
    }
  }

  // ---- basis MLP: venc(cols0-31) -> cols64-127 -> cols128-191 -> out ----
  basis_hidden<1>(hbuf, pbw0, bb0, 0, 64, wv, g, ln, lane);
  __syncthreads();
  basis_hidden<2>(hbuf, pbw1, bb1, 2, 128, wv, g, ln, lane);
  __syncthreads();
  {
    f32x4 accO = (f32x4){0.f, 0.f, 0.f, 0.f};
    #pragma unroll
    for (int kc = 0; kc < 2; ++kc) {
      half8 aw = *(const half8*)&pbwo[kc * 512 + lane * 8];
      half8 bx = *(const half8*)&hbuf[wv * 6144 + (4 + kc) * 512 + lane * 8];
      accO = MFMA32(aw, bx, accO);
    }
    if (g < 2) {   // features 0..7; one float4 store per lane, 512B/wave span
      const int ray = r0 + wv * 16 + ln;
      f32x4 bv;
      #pragma unroll
      for (int r = 0; r < 4; ++r)
        bv[r] = tanh_fast(accO[r] + bbo[g * 4 + r]);
      *(f32x4*)&wsBasis[(p * RAYS + ray) * 8 + g * 4] = bv;
    }
  }
}

// ---------------------------------------------------------------------------
// composite: per ray (block, 192 threads = 1 thread/plane):
// grid-sample sigmoid(mpi), illum = coeff . basis, clip, prefix-product scan,
// weighted sum -> out[3][1024]
// ---------------------------------------------------------------------------
__global__ __launch_bounds__(192) void composite_kernel(
    const float* __restrict__ mpi, const int* __restrict__ selection,
    const float* __restrict__ wsHs, const float* __restrict__ wsAlpha,
    const float* __restrict__ wsCoeff, const float* __restrict__ wsBasis,
    float* __restrict__ out)
{
  const int ray = blockIdx.x;
  const int p = threadIdx.x;
  const int sel = selection[ray];
  const float cx = (float)(sel % IMW), cy = (float)(sel / IMW);
  const float* H = wsHs + p * 9;
  const float pr0 = H[0] * cx + H[1] * cy + H[2];
  const float pr1 = H[3] * cx + H[4] * cy + H[5];
  const float pr2 = H[6] * cx + H[7] * cy + H[8];
  const float rx = pr0 / pr2, ry = pr1 / pr2;
  const float wx = (rx / 767.0f) * 2.0f - 1.0f;
  const float wy = (ry / 511.0f) * 2.0f - 1.0f;
  const float x = (wx + 1.0f) * 0.5f * 767.0f;
  const float y = (wy + 1.0f) * 0.5f * 511.0f;
  const float gz = -1.0f + (float)(p / 12) * (2.0f / 15.0f);
  const float z = (gz + 1.0f) * 0.5f * 15.0f;
  const float x0 = floorf(x), y0 = floorf(y), z0 = floorf(z);
  float rgb0 = 0.f, rgb1 = 0.f, rgb2 = 0.f;
  #pragma unroll
  for (int dz = 0; dz < 2; ++dz)
    #pragma unroll
    for (int dy = 0; dy < 2; ++dy)
      #pragma unroll
      for (int dx = 0; dx < 2; ++dx) {
        const float xi = x0 + (float)dx, yi = y0 + (float)dy, zi = z0 + (float)dz;
        const float w = (1.f - fabsf(x - xi)) * (1.f - fabsf(y - yi)) * (1.f - fabsf(z - zi));
        const bool valid = (xi >= 0.f) && (xi < 768.f) && (yi >= 0.f) && (yi < 512.f)
                        && (zi >= 0.f) && (zi < 16.f);
        if (valid && w != 0.f) {
          const int ix = (int)xi, iy = (int)yi, iz = (int)zi;
          const int base = iz * 3 * (IMW * IMH) + iy * IMW + ix;   // mpi[d][c][y][x]
          const float v0 = mpi[base];
          const float v1 = mpi[base + IMW * IMH];
          const float v2 = mpi[base + 2 * IMW * IMH];
          rgb0 += w * (1.f / (1.f + expf(-v0)));
          rgb1 += w * (1.f / (1.f + expf(-v1)));
          rgb2 += w * (1.f / (1.f + expf(-v2)));
        }
      }
  const float* bs = wsBasis + (p * RAYS + ray) * 8;
  const float* cf = wsCoeff + (p / 12) * 24 * RAYS + ray;
  float il0 = 0.f, il1 = 0.f, il2 = 0.f;
  #pragma unroll
  for (int j = 0; j < 8; ++j) {
    const float bj = bs[j];
    il0 += cf[j * RAYS] * bj;
    il1 += cf[(8 + j) * RAYS] * bj;
    il2 += cf[(16 + j) * RAYS] * bj;
  }
  rgb0 = fminf(fmaxf(rgb0 + il0, 0.f), 1.f);
  rgb1 = fminf(fmaxf(rgb1 + il1, 0.f), 1.f);
  rgb2 = fminf(fmaxf(rgb2 + il2, 0.f), 1.f);
  const float a = wsAlpha[p * RAYS + ray];
  const int lane = p & 63, w64 = p >> 6;
  // inclusive prefix product of (1-a) within each wave
  float xs = 1.f - a;
  #pragma unroll
  for (int off = 1; off < 64; off <<= 1) {
    const float v = __shfl_up(xs, off, 64);
    if (lane >= off) xs *= v;
  }
  __shared__ float wtot[3];
  __shared__ float part[3][3];
  if (lane == 63) wtot[w64] = xs;
  __syncthreads();
  float pre = 1.f;
  #pragma unroll
  for (int q = 0; q < 2; ++q)
    if (q < w64) pre *= wtot[q];
  float excl = __shfl_up(xs, 1, 64);
  if (lane == 0) excl = 1.f;
  const float wa = pre * excl * a;
  float s0 = wa * rgb0, s1 = wa * rgb1, s2 = wa * rgb2;
  #pragma unroll
  for (int off = 32; off >= 1; off >>= 1) {
    s0 += __shfl_down(s0, off, 64);
    s1 += __shfl_down(s1, off, 64);
    s2 += __shfl_down(s2, off, 64);
  }
  if (lane == 0) { part[w64][0] = s0; part[w64][1] = s1; part[w64][2] = s2; }
  __syncthreads();
  if (p == 0) {
    out[0 * RAYS + ray] = part[0][0] + part[1][0] + part[2][0];
    out[1 * RAYS + ray] = part[0][1] + part[1][1] + part[2][1];
    out[2 * RAYS + ray] = part[0][2] + part[1][2] + part[2][2];
  }
}

// ---------------------------------------------------------------------------
extern "C" void kernel_launch(void* const* d_in, const int* in_sizes, int n_in,
                              void* d_out, int out_size, void* d_ws, size_t ws_size,
                              hipStream_t stream)
{
  (void)in_sizes; (void)n_in; (void)out_size;
  const float* mpi    = (const float*)d_in[0];
  const float* w0     = (const float*)d_in[1];
  const float* b0     = (const float*)d_in[2];
  const float* w1     = (const float*)d_in[3];
  const float* b1     = (const float*)d_in[4];
  const float* w2     = (const float*)d_in[5];
  const float* b2     = (const float*)d_in[6];
  const float* w3     = (const float*)d_in[7];
  const float* b3     = (const float*)d_in[8];
  const float* w4     = (const float*)d_in[9];
  const float* b4     = (const float*)d_in[10];
  const float* wo     = (const float*)d_in[11];
  const float* bo     = (const float*)d_in[12];
  const float* bw0    = (const float*)d_in[13];
  const float* bb0    = (const float*)d_in[14];
  const float* bw1    = (const float*)d_in[15];
  const float* bb1    = (const float*)d_in[16];
  const float* bwo    = (const float*)d_in[17];
  const float* bbo    = (const float*)d_in[18];
  const float* ref_rT = (const float*)d_in[19];
  const float* ref_t  = (const float*)d_in[20];
  const float* ref_k  = (const float*)d_in[21];
  const float* feat_r = (const float*)d_in[22];
  const float* feat_t = (const float*)d_in[23];
  const float* feat_c = (const float*)d_in[24];
  const float* feat_k = (const float*)d_in[25];
  const float* planes = (const float*)d_in[26];
  const int*   selection = (const int*)d_in[27];
  float* outp = (float*)d_out;
  char* ws = (char*)d_ws;
  if (ws_size < (size_t)WS_NEED) return;   // workspace too small -> visible failure

  float* wsHs    = (float*)(ws + O_HS);
  float* wsKiCam = (float*)(ws + O_KICAM);
  float* wsAlpha = (float*)(ws + O_ALPHA);
  float* wsCoeff = (float*)(ws + O_COEFF);
  float* wsBasis = (float*)(ws + O_BASIS);
  _Float16* pw0  = (_Float16*)(ws + O_PW0);
  _Float16* pw1  = (_Float16*)(ws + O_PW1);
  _Float16* pw2  = (_Float16*)(ws + O_PW2);
  _Float16* pw3  = (_Float16*)(ws + O_PW3);
  _Float16* pw4  = (_Float16*)(ws + O_PW4);
  _Float16* pwo  = (_Float16*)(ws + O_PWO);
  _Float16* pbw0 = (_Float16*)(ws + O_PBW0);
  _Float16* pbw1 = (_Float16*)(ws + O_PBW1);
  _Float16* pbwo = (_Float16*)(ws + O_PBWO);

  prep_kernel<<<1, 256, 0, stream>>>(ref_rT, ref_t, ref_k, feat_r, feat_t, feat_c,
                                     feat_k, planes, wsHs, wsKiCam);
  pack_all_kernel<<<2476, 256, 0, stream>>>(w0, w1, w2, w3, w4, wo, bw0, bw1, bwo, pw0);

  mlp_kernel<<<(NPLANES * RAYS) / 64, 256, 0, stream>>>(
      selection, planes, wsHs, wsKiCam,
      pw0, pw1, pw2, pw3, pw4, pwo,
      b0, b1, b2, b3, b4, bo,
      pbw0, pbw1, pbwo, bb0, bb1, bbo,
      wsAlpha, wsCoeff, wsBasis);

  composite_kernel<<<RAYS, NPLANES, 0, stream>>>(mpi, selection, wsHs, wsAlpha,
                                                 wsCoeff, wsBasis, outp);
}

// Round 12
// 264.150 us; speedup vs baseline: 1.5498x; 1.1800x over previous
//
#include <hip/hip_runtime.h>
#include <hip/hip_bf16.h>
#include <math.h>

// ---------------------------------------------------------------------------
// MPI-NeRF style network renderer for MI355X (gfx950).
// R11: exact R7 structure (263us measured) + basis-MLP ping-pong through
//      disjoint LDS col regions (0-31 -> 64-127 -> 128-191), tail barriers
//      5 -> 3. NOTHING held live across the main-MLP layers (R9/R10 lesson:
//      any cross-layer live value spills to scratch under MFMA pressure).
// ---------------------------------------------------------------------------

typedef _Float16 half2 __attribute__((ext_vector_type(2)));
typedef _Float16 half4 __attribute__((ext_vector_type(4)));
typedef _Float16 half8 __attribute__((ext_vector_type(8)));
typedef float f32x4 __attribute__((ext_vector_type(4)));

#if __has_builtin(__builtin_amdgcn_mfma_f32_16x16x32_f16)
#define MFMA32(a, b, c) __builtin_amdgcn_mfma_f32_16x16x32_f16((a), (b), (c), 0, 0, 0)
#else
#define MFMA32(a, b, c) (c)   // host-pass placeholder (never executed)
#endif

#define NPLANES 192
#define RAYS    1024
#define IMW     768
#define IMH     512

// fragment-order index into hbuf: point i (0..63), feature/column c (0..383)
// layout [pt(4)][kc(12)][g(4)][ln(16)][j(8)], strides 6144/512/128/8/1 halves
#define FR(i, c) ((((i) >> 4) * 6144) + (((c) >> 5) * 512) + ((((c) >> 3) & 3) * 128) \
                  + (((i) & 15) * 8) + ((c) & 7))

// sin(2*pi*rev) via HW: fract to [0,1) then v_sin
__device__ __forceinline__ float sin_rev(float rev) {
  float f, r;
  asm("v_fract_f32 %0, %1" : "=v"(f) : "v"(rev));
  asm("v_sin_f32 %0, %1" : "=v"(r) : "v"(f));
  return r;
}
__device__ __forceinline__ float exp2_fast(float x) {
  float r;
  asm("v_exp_f32 %0, %1" : "=v"(r) : "v"(x));
  return r;
}
__device__ __forceinline__ float rcp_fast(float x) {
  float r;
  asm("v_rcp_f32 %0, %1" : "=v"(r) : "v"(x));
  return r;
}
__device__ __forceinline__ float tanh_fast(float x) {
  const float xc = fminf(fmaxf(x, -30.f), 30.f);
  const float t = exp2_fast(xc * 2.885390082f);   // 2*log2(e)
  return (t - 1.f) * rcp_fast(t + 1.f);
}
__device__ __forceinline__ float sig5_fast(float o) {
  const float u = exp2_fast((5.f - o) * 1.4426950f);
  return rcp_fast(1.f + u);
}

// leaky-relu + packed f32x4 -> f16x4 (RTZ)
__device__ __forceinline__ half4 leaky_pack(f32x4 a) {
  const float v0 = fmaxf(a[0], a[0] * 0.01f);
  const float v1 = fmaxf(a[1], a[1] * 0.01f);
  const float v2 = fmaxf(a[2], a[2] * 0.01f);
  const float v3 = fmaxf(a[3], a[3] * 0.01f);
  const half2 lo = __builtin_bit_cast(half2, __builtin_amdgcn_cvt_pkrtz(v0, v1));
  const half2 hi = __builtin_bit_cast(half2, __builtin_amdgcn_cvt_pkrtz(v2, v3));
  return __builtin_shufflevector(lo, hi, 0, 1, 2, 3);
}

// ---- workspace layout (bytes), all offsets 256-aligned ----
// Side outputs PLANE-MAJOR: alpha[p][ray], basis[p][ray][8], coeff[pg][24][ray]
#define O_HS     0           // Hs[192][9] f32                     (6912)
#define O_KICAM  7168        // ki[9], cam[3] f32                  (48)
#define O_ALPHA  7424        // alpha[p][ray] f32                  (786432)
#define O_COEFF  793856      // coeff[pg][24][ray] f32             (1572864)
#define O_PW0    2366720     // packed weights, contiguous (see pack_all)
#define O_PW1    2415872
#define O_PW2    2710784
#define O_PW3    3005696
#define O_PW4    3300608
#define O_PWO    3595520
#define O_PBW0   3620096
#define O_PBW1   3624192
#define O_PBWO   3632384
#define O_BASIS  3634432     // basis[p][ray][8] f32               (6291456)
#define WS_NEED  (O_BASIS + 6291456)

// ---------------------------------------------------------------------------
// prep: homographies Hs[p], ki, camera
// ---------------------------------------------------------------------------
__global__ void prep_kernel(const float* __restrict__ ref_rT, const float* __restrict__ ref_t,
                            const float* __restrict__ ref_k, const float* __restrict__ feat_r,
                            const float* __restrict__ feat_t, const float* __restrict__ feat_center,
                            const float* __restrict__ feat_k, const float* __restrict__ planes,
                            float* __restrict__ wsHs, float* __restrict__ wsKiCam)
{
  __shared__ float sKi[9], sHa[9], sHb[9], sHc[1];
  if (threadIdx.x == 0) {
    float a = feat_k[0], b = feat_k[1], c = feat_k[2];
    float d = feat_k[3], e = feat_k[4], f = feat_k[5];
    float g = feat_k[6], h = feat_k[7], i = feat_k[8];
    float A = e * i - f * h, B = -(d * i - f * g), C = d * h - e * g;
    float det = a * A + b * B + c * C;
    float id = 1.0f / det;
    float ki[9];
    ki[0] = A * id;             ki[1] = -(b * i - c * h) * id;  ki[2] = (b * f - c * e) * id;
    ki[3] = B * id;             ki[4] = (a * i - c * g) * id;   ki[5] = -(a * f - c * d) * id;
    ki[6] = C * id;             ki[7] = -(a * h - b * g) * id;  ki[8] = (a * e - b * d) * id;
    float nr[9];
    for (int r2 = 0; r2 < 3; ++r2)
      for (int c2 = 0; c2 < 3; ++c2) {
        float s = 0.f;
        for (int k2 = 0; k2 < 3; ++k2) s += feat_r[r2 * 3 + k2] * ref_rT[k2 * 3 + c2];
        nr[r2 * 3 + c2] = s;
      }
    float ntv[3];
    for (int r2 = 0; r2 < 3; ++r2) {
      float s = 0.f;
      for (int k2 = 0; k2 < 3; ++k2) s += nr[r2 * 3 + k2] * ref_t[k2];
      ntv[r2] = -s + feat_t[r2];
    }
    float Ha[9];
    for (int r2 = 0; r2 < 3; ++r2)
      for (int c2 = 0; c2 < 3; ++c2) Ha[r2 * 3 + c2] = nr[c2 * 3 + r2];  // new_r^T
    float u[3];
    for (int r2 = 0; r2 < 3; ++r2) {
      float s = 0.f;
      for (int k2 = 0; k2 < 3; ++k2) s += Ha[r2 * 3 + k2] * ntv[k2];
      u[r2] = s;
    }
    float Hb[9];
    for (int r2 = 0; r2 < 3; ++r2)
      for (int c2 = 0; c2 < 3; ++c2) Hb[r2 * 3 + c2] = u[r2] * Ha[6 + c2];
    float cam[3];
    for (int r2 = 0; r2 < 3; ++r2) {
      float s = 0.f;
      for (int k2 = 0; k2 < 3; ++k2) s += ref_rT[k2 * 3 + r2] * feat_center[k2];
      cam[r2] = s + ref_t[r2];
    }
    for (int j = 0; j < 9; ++j) { sKi[j] = ki[j]; sHa[j] = Ha[j]; sHb[j] = Hb[j]; }
    sHc[0] = u[2];
    for (int j = 0; j < 9; ++j) wsKiCam[j] = ki[j];
    for (int j = 0; j < 3; ++j) wsKiCam[9 + j] = cam[j];
  }
  __syncthreads();
  int p = threadIdx.x;
  if (p < NPLANES) {
    float dnm = -planes[p] - sHc[0];
    float T[9];
    for (int j = 0; j < 9; ++j) T[j] = sHa[j] + sHb[j] / dnm;
    float U[9];
    for (int r2 = 0; r2 < 3; ++r2)
      for (int c2 = 0; c2 < 3; ++c2) {
        float s = 0.f;
        for (int k2 = 0; k2 < 3; ++k2) s += ref_k[r2 * 3 + k2] * T[k2 * 3 + c2];
        U[r2 * 3 + c2] = s;
      }
    for (int r2 = 0; r2 < 3; ++r2)
      for (int c2 = 0; c2 < 3; ++c2) {
        float s = 0.f;
        for (int k2 = 0; k2 < 3; ++k2) s += U[r2 * 3 + k2] * sKi[k2 * 3 + c2];
        wsHs[p * 9 + r2 * 3 + c2] = s;
      }
  }
}

// ---------------------------------------------------------------------------
// pack_all: every weight matrix -> f16 fragment blocks for 16x16x32.
// dst block (kc,t) holds 512 halves [g(4)][ln(16)][j(8)]:
//   value = W[kc*32 + g*8 + j][t*16 + ln]
// ---------------------------------------------------------------------------
__global__ void pack_all_kernel(const float* __restrict__ w0, const float* __restrict__ w1,
                                const float* __restrict__ w2, const float* __restrict__ w3,
                                const float* __restrict__ w4, const float* __restrict__ wo,
                                const float* __restrict__ bw0, const float* __restrict__ bw1,
                                const float* __restrict__ bwo, _Float16* __restrict__ dst)
{
  const int idx = blockIdx.x * 256 + threadIdx.x;
  const float* src; int Ksrc, Nsrc, NP, l;
  if (idx < 24576)       { src = w0;  Ksrc = 56;  Nsrc = 384; NP = 384; l = idx; }
  else if (idx < 172032) { src = w1;  Ksrc = 384; Nsrc = 384; NP = 384; l = idx - 24576; }
  else if (idx < 319488) { src = w2;  Ksrc = 384; Nsrc = 384; NP = 384; l = idx - 172032; }
  else if (idx < 466944) { src = w3;  Ksrc = 384; Nsrc = 384; NP = 384; l = idx - 319488; }
  else if (idx < 614400) { src = w4;  Ksrc = 384; Nsrc = 384; NP = 384; l = idx - 466944; }
  else if (idx < 626688) { src = wo;  Ksrc = 384; Nsrc = 25;  NP = 32;  l = idx - 614400; }
  else if (idx < 628736) { src = bw0; Ksrc = 12;  Nsrc = 64;  NP = 64;  l = idx - 626688; }
  else if (idx < 632832) { src = bw1; Ksrc = 64;  Nsrc = 64;  NP = 64;  l = idx - 628736; }
  else if (idx < 633856) { src = bwo; Ksrc = 64;  Nsrc = 8;   NP = 16;  l = idx - 632832; }
  else return;
  const int within = l & 511, blk = l >> 9;
  const int kg = within >> 7, ln = (within >> 3) & 15, j = within & 7;
  const int ntiles = NP >> 4;
  const int nt = blk % ntiles, kc = blk / ntiles;
  const int k = kc * 32 + kg * 8 + j, nn = nt * 16 + ln;
  const float v = (k < Ksrc && nn < Nsrc) ? src[k * Nsrc + nn] : 0.0f;
  dst[idx] = (_Float16)v;
}

// ---------------------------------------------------------------------------
// main MLP kernel: 64 points per block (one plane), 256 threads = 4 waves.
// Weights = A (m=feature), activations = B (n=point). 16x16x32 MFMA.
// hbuf fragment-ordered; lane reads B-frag at hb[pt*6144 + kc*512 + lane*8].
// ---------------------------------------------------------------------------
template <int NKC>
__device__ __forceinline__ void hidden_layer(_Float16* hb, const _Float16* __restrict__ wl,
                                             const float* __restrict__ bias,
                                             int wv, int g, int ln, int lane)
{
  f32x4 acc[6][4];   // [feature-tile][point-tile]
  #pragma unroll
  for (int ft = 0; ft < 6; ++ft) {
    const f32x4 bv4 = *(const f32x4*)&bias[(wv * 6 + ft) * 16 + g * 4];
    #pragma unroll
    for (int pt = 0; pt < 4; ++pt) acc[ft][pt] = bv4;
  }
  #pragma unroll 2
  for (int kc = 0; kc < NKC; ++kc) {
    half8 aw[6];
    #pragma unroll
    for (int ft = 0; ft < 6; ++ft)
      aw[ft] = *(const half8*)&wl[(kc * 24 + wv * 6 + ft) * 512 + lane * 8];
    half8 bx[4];
    #pragma unroll
    for (int pt = 0; pt < 4; ++pt)
      bx[pt] = *(const half8*)&hb[pt * 6144 + kc * 512 + lane * 8];
    #pragma unroll
    for (int ft = 0; ft < 6; ++ft)
      #pragma unroll
      for (int pt = 0; pt < 4; ++pt)
        acc[ft][pt] = MFMA32(aw[ft], bx[pt], acc[ft][pt]);
  }
  __syncthreads();   // all reads of hb done before overwrite
  #pragma unroll
  for (int pt = 0; pt < 4; ++pt)
    #pragma unroll
    for (int ft = 0; ft < 6; ++ft) {
      const int f0 = wv * 96 + ft * 16 + g * 4;
      *(half4*)&hb[pt * 6144 + (f0 >> 5) * 512 + ((f0 >> 3) & 3) * 128 + ln * 8 + (f0 & 7)] =
          leaky_pack(acc[ft][pt]);
    }
  __syncthreads();
}

// basis layer: ping-pong through disjoint LDS col regions; no internal
// barriers (read region and write region never overlap).
// Reads cols [src_kc*32, src_kc*32+NKC*32), writes features dstC + wv*16+g*4.
template <int NKC>
__device__ __forceinline__ void basis_hidden(_Float16* hb, const _Float16* __restrict__ wl,
                                             const float* __restrict__ bias,
                                             int src_kc, int dstC,
                                             int wv, int g, int ln, int lane)
{
  f32x4 acc[4];      // [point-tile], this wave owns feature-tile wv
  const f32x4 bv4 = *(const f32x4*)&bias[wv * 16 + g * 4];
  #pragma unroll
  for (int pt = 0; pt < 4; ++pt) acc[pt] = bv4;
  #pragma unroll
  for (int kc = 0; kc < NKC; ++kc) {
    half8 aw = *(const half8*)&wl[(kc * 4 + wv) * 512 + lane * 8];
    #pragma unroll
    for (int pt = 0; pt < 4; ++pt) {
      half8 bx = *(const half8*)&hb[pt * 6144 + (src_kc + kc) * 512 + lane * 8];
      acc[pt] = MFMA32(aw, bx, acc[pt]);
    }
  }
  const int f0 = dstC + wv * 16 + g * 4;
  #pragma unroll
  for (int pt = 0; pt < 4; ++pt)
    *(half4*)&hb[pt * 6144 + (f0 >> 5) * 512 + ((f0 >> 3) & 3) * 128 + ln * 8 + (f0 & 7)] =
        leaky_pack(acc[pt]);
}

__global__ __launch_bounds__(256, 3) void mlp_kernel(
    const int* __restrict__ selection, const float* __restrict__ planes,
    const float* __restrict__ wsHs, const float* __restrict__ wsKiCam,
    const _Float16* __restrict__ pw0, const _Float16* __restrict__ pw1,
    const _Float16* __restrict__ pw2, const _Float16* __restrict__ pw3,
    const _Float16* __restrict__ pw4, const _Float16* __restrict__ pwo,
    const float* __restrict__ b0, const float* __restrict__ b1,
    const float* __restrict__ b2, const float* __restrict__ b3,
    const float* __restrict__ b4, const float* __restrict__ bo,
    const _Float16* __restrict__ pbw0, const _Float16* __restrict__ pbw1,
    const _Float16* __restrict__ pbwo,
    const float* __restrict__ bb0, const float* __restrict__ bb1,
    const float* __restrict__ bbo,
    float* __restrict__ wsAlpha, float* __restrict__ wsCoeff, float* __restrict__ wsBasis)
{
  __shared__ _Float16 hbuf[4 * 6144];   // 49152 B, fragment-ordered
  const int t = threadIdx.x;
  const int m0 = blockIdx.x * 64;
  const int p = m0 >> 10;       // plane (blocks never straddle planes: 16 blocks/plane)
  const int r0 = m0 & 1023;
  const int lane = t & 63, wv = t >> 6;
  const int g = lane >> 4, ln = lane & 15;

  // ---- phase 1: positional encoding -> cols 0..63 (56 real + 8 zero pad) ----
  {
    const int i = t >> 2, q = t & 3;   // 4 threads per point
    const int ray = r0 + i;
    const int sel = selection[ray];
    const float cx = (float)(sel % IMW), cy = (float)(sel / IMW);
    const float* H = wsHs + p * 9;
    const float pr0 = H[0] * cx + H[1] * cy + H[2];
    const float pr1 = H[3] * cx + H[4] * cy + H[5];
    const float pr2 = H[6] * cx + H[7] * cy + H[8];
    const float rx = pr0 / pr2, ry = pr1 / pr2;
    const float wx = (rx / 767.0f) * 2.0f - 1.0f;
    const float wy = (ry / 511.0f) * 2.0f - 1.0f;
    const float zc = -1.0f + (float)p * (2.0f / 191.0f);
    // sin(base * pi/2 * 2^c) = sin_rev(base * 2^(c-2)); cos = sin_rev(+0.25)
    #pragma unroll
    for (int cc = 0; cc < 7; ++cc) {
      const int c = q * 7 + cc;
      float base; int e;
      if (c < 10)      { base = wx; e = c; }
      else if (c < 20) { base = wy; e = c - 10; }
      else             { base = zc; e = c - 20; }
      const float rev = ldexpf(base, e - 2);
      hbuf[FR(i, c)]      = (_Float16)sin_rev(rev);
      hbuf[FR(i, c + 28)] = (_Float16)sin_rev(rev + 0.25f);
    }
    hbuf[FR(i, 56 + q)] = (_Float16)0.f;
    hbuf[FR(i, 60 + q)] = (_Float16)0.f;
  }
  __syncthreads();

  // ---- main MLP ----
  hidden_layer<2>(hbuf, pw0, b0, wv, g, ln, lane);
  hidden_layer<12>(hbuf, pw1, b1, wv, g, ln, lane);
  hidden_layer<12>(hbuf, pw2, b2, wv, g, ln, lane);
  hidden_layer<12>(hbuf, pw3, b3, wv, g, ln, lane);
  hidden_layer<12>(hbuf, pw4, b4, wv, g, ln, lane);

  // ---- output layer (25 features padded to 32 = 2 ft-tiles), wave owns pt=wv ----
  f32x4 acc2[2];
  {
    #pragma unroll
    for (int ft = 0; ft < 2; ++ft) {
      f32x4 bv;
      #pragma unroll
      for (int r = 0; r < 4; ++r) {
        const int f = ft * 16 + g * 4 + r;
        bv[r] = (f < 25) ? bo[f] : 0.f;
      }
      acc2[ft] = bv;
    }
    #pragma unroll 2
    for (int kc = 0; kc < 12; ++kc) {
      half8 bx = *(const half8*)&hbuf[wv * 6144 + kc * 512 + lane * 8];
      #pragma unroll
      for (int ft = 0; ft < 2; ++ft) {
        half8 aw = *(const half8*)&pwo[(kc * 2 + ft) * 512 + lane * 8];
        acc2[ft] = MFMA32(aw, bx, acc2[ft]);
      }
    }
    __syncthreads();   // all hbuf reads done
  }

  // ---- view-direction encoding -> cols 0..15 (12 real + 4 zero pad) ----
  {
    const int i = t >> 2, q = t & 3;
    const int ray = r0 + i;
    const int sel = selection[ray];
    const float cx = (float)(sel % IMW), cy = (float)(sel / IMW);
    const float* H = wsHs + p * 9;
    const float pr0 = H[0] * cx + H[1] * cy + H[2];
    const float pr1 = H[3] * cx + H[4] * cy + H[5];
    const float pr2 = H[6] * cx + H[7] * cy + H[8];
    const float rx = pr0 / pr2, ry = pr1 / pr2;
    const float pd = planes[p];
    const float* ki = wsKiCam; const float* cam = wsKiCam + 9;
    const float c0 = rx * pd, c1 = ry * pd, c2 = pd;
    const float vx0 = ki[0] * c0 + ki[1] * c1 + ki[2] * c2 - cam[0];
    const float vy0 = ki[3] * c0 + ki[4] * c1 + ki[5] * c2 - cam[1];
    const float vz0 = ki[6] * c0 + ki[7] * c1 + ki[8] * c2 - cam[2];
    const float nrm = sqrtf(vx0 * vx0 + vy0 * vy0 + vz0 * vz0) + 1e-7f;
    const float vx = vx0 / nrm, vy = vy0 / nrm;
    // sin(pi/2 * v * 2^e) = sin_rev(v * 2^(e-2))
    #pragma unroll
    for (int cc = 0; cc < 4; ++cc) {
      const int c = q * 4 + cc;
      float v;
      if (c < 6) {
        v = sin_rev(ldexpf((c < 3) ? vx : vy, (c % 3) - 2));
      } else if (c < 12) {
        const int c6 = c - 6;
        v = sin_rev(ldexpf((c6 < 3) ? vx : vy, (c6 % 3) - 2) + 0.25f);
      } else v = 0.f;
      hbuf[FR(i, c)] = (_Float16)v;
    }
  }
  __syncthreads();   // venc visible to all waves

  // ---- alpha / coeff epilogue from output-layer registers (plane-major) ----
  // (global stores only; overlaps with basis MFMA below — no barrier needed)
  {
    if (g == 0) {   // feature 0 lives in reg r=0 of g=0, ft=0
      const int ray = r0 + wv * 16 + ln;
      wsAlpha[p * RAYS + ray] = sig5_fast(acc2[0][0]);
    }
    if ((p % 12) == 0) {
      const int pg = p / 12;
      const int ray = r0 + wv * 16 + ln;
      #pragma unroll
      for (int ft = 0; ft < 2; ++ft)
        #pragma unroll
        for (int r = 0; r < 4; ++r) {
          const int f = ft * 16 + g * 4 + r;
          if (f >= 1 && f < 25)
            wsCoeff[(pg * 24 + (f - 1)) * RAYS + ray] = tanh_fast(acc2[ft][r]);
        }
    }
  }

  // ---- basis MLP ping-pong: venc(cols0-31) -> 64-127 -> 128-191 -> out ----
  basis_hidden<1>(hbuf, pbw0, bb0, 0, 64, wv, g, ln, lane);
  __syncthreads();
  basis_hidden<2>(hbuf, pbw1, bb1, 2, 128, wv, g, ln, lane);
  __syncthreads();
  {
    f32x4 accO = (f32x4){0.f, 0.f, 0.f, 0.f};
    #pragma unroll
    for (int kc = 0; kc < 2; ++kc) {
      half8 aw = *(const half8*)&pbwo[kc * 512 + lane * 8];
      half8 bx = *(const half8*)&hbuf[wv * 6144 + (4 + kc) * 512 + lane * 8];
      accO = MFMA32(aw, bx, accO);
    }
    if (g < 2) {   // features 0..7; one float4 store per lane, 512B/wave span
      const int ray = r0 + wv * 16 + ln;
      f32x4 bv;
      #pragma unroll
      for (int r = 0; r < 4; ++r)
        bv[r] = tanh_fast(accO[r] + bbo[g * 4 + r]);
      *(f32x4*)&wsBasis[(p * RAYS + ray) * 8 + g * 4] = bv;
    }
  }
}

// ---------------------------------------------------------------------------
// composite: per ray (block, 192 threads = 1 thread/plane):
// grid-sample sigmoid(mpi), illum = coeff . basis, clip, prefix-product scan,
// weighted sum -> out[3][1024]
// ---------------------------------------------------------------------------
__global__ __launch_bounds__(192) void composite_kernel(
    const float* __restrict__ mpi, const int* __restrict__ selection,
    const float* __restrict__ wsHs, const float* __restrict__ wsAlpha,
    const float* __restrict__ wsCoeff, const float* __restrict__ wsBasis,
    float* __restrict__ out)
{
  const int ray = blockIdx.x;
  const int p = threadIdx.x;
  const int sel = selection[ray];
  const float cx = (float)(sel % IMW), cy = (float)(sel / IMW);
  const float* H = wsHs + p * 9;
  const float pr0 = H[0] * cx + H[1] * cy + H[2];
  const float pr1 = H[3] * cx + H[4] * cy + H[5];
  const float pr2 = H[6] * cx + H[7] * cy + H[8];
  const float rx = pr0 / pr2, ry = pr1 / pr2;
  const float wx = (rx / 767.0f) * 2.0f - 1.0f;
  const float wy = (ry / 511.0f) * 2.0f - 1.0f;
  const float x = (wx + 1.0f) * 0.5f * 767.0f;
  const float y = (wy + 1.0f) * 0.5f * 511.0f;
  const float gz = -1.0f + (float)(p / 12) * (2.0f / 15.0f);
  const float z = (gz + 1.0f) * 0.5f * 15.0f;
  const float x0 = floorf(x), y0 = floorf(y), z0 = floorf(z);
  float rgb0 = 0.f, rgb1 = 0.f, rgb2 = 0.f;
  #pragma unroll
  for (int dz = 0; dz < 2; ++dz)
    #pragma unroll
    for (int dy = 0; dy < 2; ++dy)
      #pragma unroll
      for (int dx = 0; dx < 2; ++dx) {
        const float xi = x0 + (float)dx, yi = y0 + (float)dy, zi = z0 + (float)dz;
        const float w = (1.f - fabsf(x - xi)) * (1.f - fabsf(y - yi)) * (1.f - fabsf(z - zi));
        const bool valid = (xi >= 0.f) && (xi < 768.f) && (yi >= 0.f) && (yi < 512.f)
                        && (zi >= 0.f) && (zi < 16.f);
        if (valid && w != 0.f) {
          const int ix = (int)xi, iy = (int)yi, iz = (int)zi;
          const int base = iz * 3 * (IMW * IMH) + iy * IMW + ix;   // mpi[d][c][y][x]
          const float v0 = mpi[base];
          const float v1 = mpi[base + IMW * IMH];
          const float v2 = mpi[base + 2 * IMW * IMH];
          rgb0 += w * (1.f / (1.f + expf(-v0)));
          rgb1 += w * (1.f / (1.f + expf(-v1)));
          rgb2 += w * (1.f / (1.f + expf(-v2)));
        }
      }
  const float* bs = wsBasis + (p * RAYS + ray) * 8;
  const float* cf = wsCoeff + (p / 12) * 24 * RAYS + ray;
  float il0 = 0.f, il1 = 0.f, il2 = 0.f;
  #pragma unroll
  for (int j = 0; j < 8; ++j) {
    const float bj = bs[j];
    il0 += cf[j * RAYS] * bj;
    il1 += cf[(8 + j) * RAYS] * bj;
    il2 += cf[(16 + j) * RAYS] * bj;
  }
  rgb0 = fminf(fmaxf(rgb0 + il0, 0.f), 1.f);
  rgb1 = fminf(fmaxf(rgb1 + il1, 0.f), 1.f);
  rgb2 = fminf(fmaxf(rgb2 + il2, 0.f), 1.f);
  const float a = wsAlpha[p * RAYS + ray];
  const int lane = p & 63, w64 = p >> 6;
  // inclusive prefix product of (1-a) within each wave
  float xs = 1.f - a;
  #pragma unroll
  for (int off = 1; off < 64; off <<= 1) {
    const float v = __shfl_up(xs, off, 64);
    if (lane >= off) xs *= v;
  }
  __shared__ float wtot[3];
  __shared__ float part[3][3];
  if (lane == 63) wtot[w64] = xs;
  __syncthreads();
  float pre = 1.f;
  #pragma unroll
  for (int q = 0; q < 2; ++q)
    if (q < w64) pre *= wtot[q];
  float excl = __shfl_up(xs, 1, 64);
  if (lane == 0) excl = 1.f;
  const float wa = pre * excl * a;
  float s0 = wa * rgb0, s1 = wa * rgb1, s2 = wa * rgb2;
  #pragma unroll
  for (int off = 32; off >= 1; off >>= 1) {
    s0 += __shfl_down(s0, off, 64);
    s1 += __shfl_down(s1, off, 64);
    s2 += __shfl_down(s2, off, 64);
  }
  if (lane == 0) { part[w64][0] = s0; part[w64][1] = s1; part[w64][2] = s2; }
  __syncthreads();
  if (p == 0) {
    out[0 * RAYS + ray] = part[0][0] + part[1][0] + part[2][0];
    out[1 * RAYS + ray] = part[0][1] + part[1][1] + part[2][1];
    out[2 * RAYS + ray] = part[0][2] + part[1][2] + part[2][2];
  }
}

// ---------------------------------------------------------------------------
extern "C" void kernel_launch(void* const* d_in, const int* in_sizes, int n_in,
                              void* d_out, int out_size, void* d_ws, size_t ws_size,
                              hipStream_t stream)
{
  (void)in_sizes; (void)n_in; (void)out_size;
  const float* mpi    = (const float*)d_in[0];
  const float* w0     = (const float*)d_in[1];
  const float* b0     = (const float*)d_in[2];
  const float* w1     = (const float*)d_in[3];
  const float* b1     = (const float*)d_in[4];
  const float* w2     = (const float*)d_in[5];
  const float* b2     = (const float*)d_in[6];
  const float* w3     = (const float*)d_in[7];
  const float* b3     = (const float*)d_in[8];
  const float* w4     = (const float*)d_in[9];
  const float* b4     = (const float*)d_in[10];
  const float* wo     = (const float*)d_in[11];
  const float* bo     = (const float*)d_in[12];
  const float* bw0    = (const float*)d_in[13];
  const float* bb0    = (const float*)d_in[14];
  const float* bw1    = (const float*)d_in[15];
  const float* bb1    = (const float*)d_in[16];
  const float* bwo    = (const float*)d_in[17];
  const float* bbo    = (const float*)d_in[18];
  const float* ref_rT = (const float*)d_in[19];
  const float* ref_t  = (const float*)d_in[20];
  const float* ref_k  = (const float*)d_in[21];
  const float* feat_r = (const float*)d_in[22];
  const float* feat_t = (const float*)d_in[23];
  const float* feat_c = (const float*)d_in[24];
  const float* feat_k = (const float*)d_in[25];
  const float* planes = (const float*)d_in[26];
  const int*   selection = (const int*)d_in[27];
  float* outp = (float*)d_out;
  char* ws = (char*)d_ws;
  if (ws_size < (size_t)WS_NEED) return;   // workspace too small -> visible failure

  float* wsHs    = (float*)(ws + O_HS);
  float* wsKiCam = (float*)(ws + O_KICAM);
  float* wsAlpha = (float*)(ws + O_ALPHA);
  float* wsCoeff = (float*)(ws + O_COEFF);
  float* wsBasis = (float*)(ws + O_BASIS);
  _Float16* pw0  = (_Float16*)(ws + O_PW0);
  _Float16* pw1  = (_Float16*)(ws + O_PW1);
  _Float16* pw2  = (_Float16*)(ws + O_PW2);
  _Float16* pw3  = (_Float16*)(ws + O_PW3);
  _Float16* pw4  = (_Float16*)(ws + O_PW4);
  _Float16* pwo  = (_Float16*)(ws + O_PWO);
  _Float16* pbw0 = (_Float16*)(ws + O_PBW0);
  _Float16* pbw1 = (_Float16*)(ws + O_PBW1);
  _Float16* pbwo = (_Float16*)(ws + O_PBWO);

  prep_kernel<<<1, 256, 0, stream>>>(ref_rT, ref_t, ref_k, feat_r, feat_t, feat_c,
                                     feat_k, planes, wsHs, wsKiCam);
  pack_all_kernel<<<2476, 256, 0, stream>>>(w0, w1, w2, w3, w4, wo, bw0, bw1, bwo, pw0);

  mlp_kernel<<<(NPLANES * RAYS) / 64, 256, 0, stream>>>(
      selection, planes, wsHs, wsKiCam,
      pw0, pw1, pw2, pw3, pw4, pwo,
      b0, b1, b2, b3, b4, bo,
      pbw0, pbw1, pbwo, bb0, bb1, bbo,
      wsAlpha, wsCoeff, wsBasis);

  composite_kernel<<<RAYS, NPLANES, 0, stream>>>(mpi, selection, wsHs, wsAlpha,
                                                 wsCoeff, wsBasis, outp);
}

// Round 13
// 258.375 us; speedup vs baseline: 1.5845x; 1.0224x over previous
//
#include <hip/hip_runtime.h>
#include <hip/hip_bf16.h>
#include <math.h>

// ---------------------------------------------------------------------------
// MPI-NeRF style network renderer for MI355X (gfx950).
// R12: R11 base (264us) + (a) isolated s_setprio(1) around MFMA k-loops
//      (blocks are barrier-independent, attn-like regime where T5 helps),
//      (b) leaky slope applied post-pack as v_pk_mul_f16 + v_pk_max_f16
//      (4 packed ops/quad vs 10 scalar f32 ops). Nothing else changed.
// ---------------------------------------------------------------------------

typedef _Float16 half2 __attribute__((ext_vector_type(2)));
typedef _Float16 half4 __attribute__((ext_vector_type(4)));
typedef _Float16 half8 __attribute__((ext_vector_type(8)));
typedef float f32x4 __attribute__((ext_vector_type(4)));

#if __has_builtin(__builtin_amdgcn_mfma_f32_16x16x32_f16)
#define MFMA32(a, b, c) __builtin_amdgcn_mfma_f32_16x16x32_f16((a), (b), (c), 0, 0, 0)
#else
#define MFMA32(a, b, c) (c)   // host-pass placeholder (never executed)
#endif

#define NPLANES 192
#define RAYS    1024
#define IMW     768
#define IMH     512

// fragment-order index into hbuf: point i (0..63), feature/column c (0..383)
// layout [pt(4)][kc(12)][g(4)][ln(16)][j(8)], strides 6144/512/128/8/1 halves
#define FR(i, c) ((((i) >> 4) * 6144) + (((c) >> 5) * 512) + ((((c) >> 3) & 3) * 128) \
                  + (((i) & 15) * 8) + ((c) & 7))

// sin(2*pi*rev) via HW: fract to [0,1) then v_sin
__device__ __forceinline__ float sin_rev(float rev) {
  float f, r;
  asm("v_fract_f32 %0, %1" : "=v"(f) : "v"(rev));
  asm("v_sin_f32 %0, %1" : "=v"(r) : "v"(f));
  return r;
}
__device__ __forceinline__ float exp2_fast(float x) {
  float r;
  asm("v_exp_f32 %0, %1" : "=v"(r) : "v"(x));
  return r;
}
__device__ __forceinline__ float rcp_fast(float x) {
  float r;
  asm("v_rcp_f32 %0, %1" : "=v"(r) : "v"(x));
  return r;
}
__device__ __forceinline__ float tanh_fast(float x) {
  const float xc = fminf(fmaxf(x, -30.f), 30.f);
  const float t = exp2_fast(xc * 2.885390082f);   // 2*log2(e)
  return (t - 1.f) * rcp_fast(t + 1.f);
}
__device__ __forceinline__ float sig5_fast(float o) {
  const float u = exp2_fast((5.f - o) * 1.4426950f);
  return rcp_fast(1.f + u);
}

// packed f32x4 -> f16x4 (RTZ), then leaky in packed f16:
// max(h, 0.01*h) picks h for h>=0 and 0.01h for h<0.
__device__ __forceinline__ half4 leaky_pack(f32x4 a) {
  const half2 lo = __builtin_bit_cast(half2, __builtin_amdgcn_cvt_pkrtz(a[0], a[1]));
  const half2 hi = __builtin_bit_cast(half2, __builtin_amdgcn_cvt_pkrtz(a[2], a[3]));
  half4 h = __builtin_shufflevector(lo, hi, 0, 1, 2, 3);
  half4 s = h * (_Float16)0.01f;
#if __has_builtin(__builtin_elementwise_max)
  return __builtin_elementwise_max(h, s);
#else
  half4 r;
  #pragma unroll
  for (int k = 0; k < 4; ++k) r[k] = (h[k] >= s[k]) ? h[k] : s[k];
  return r;
#endif
}

// ---- workspace layout (bytes), all offsets 256-aligned ----
// Side outputs PLANE-MAJOR: alpha[p][ray], basis[p][ray][8], coeff[pg][24][ray]
#define O_HS     0           // Hs[192][9] f32                     (6912)
#define O_KICAM  7168        // ki[9], cam[3] f32                  (48)
#define O_ALPHA  7424        // alpha[p][ray] f32                  (786432)
#define O_COEFF  793856      // coeff[pg][24][ray] f32             (1572864)
#define O_PW0    2366720     // packed weights, contiguous (see pack_all)
#define O_PW1    2415872
#define O_PW2    2710784
#define O_PW3    3005696
#define O_PW4    3300608
#define O_PWO    3595520
#define O_PBW0   3620096
#define O_PBW1   3624192
#define O_PBWO   3632384
#define O_BASIS  3634432     // basis[p][ray][8] f32               (6291456)
#define WS_NEED  (O_BASIS + 6291456)

// ---------------------------------------------------------------------------
// prep: homographies Hs[p], ki, camera
// ---------------------------------------------------------------------------
__global__ void prep_kernel(const float* __restrict__ ref_rT, const float* __restrict__ ref_t,
                            const float* __restrict__ ref_k, const float* __restrict__ feat_r,
                            const float* __restrict__ feat_t, const float* __restrict__ feat_center,
                            const float* __restrict__ feat_k, const float* __restrict__ planes,
                            float* __restrict__ wsHs, float* __restrict__ wsKiCam)
{
  __shared__ float sKi[9], sHa[9], sHb[9], sHc[1];
  if (threadIdx.x == 0) {
    float a = feat_k[0], b = feat_k[1], c = feat_k[2];
    float d = feat_k[3], e = feat_k[4], f = feat_k[5];
    float g = feat_k[6], h = feat_k[7], i = feat_k[8];
    float A = e * i - f * h, B = -(d * i - f * g), C = d * h - e * g;
    float det = a * A + b * B + c * C;
    float id = 1.0f / det;
    float ki[9];
    ki[0] = A * id;             ki[1] = -(b * i - c * h) * id;  ki[2] = (b * f - c * e) * id;
    ki[3] = B * id;             ki[4] = (a * i - c * g) * id;   ki[5] = -(a * f - c * d) * id;
    ki[6] = C * id;             ki[7] = -(a * h - b * g) * id;  ki[8] = (a * e - b * d) * id;
    float nr[9];
    for (int r2 = 0; r2 < 3; ++r2)
      for (int c2 = 0; c2 < 3; ++c2) {
        float s = 0.f;
        for (int k2 = 0; k2 < 3; ++k2) s += feat_r[r2 * 3 + k2] * ref_rT[k2 * 3 + c2];
        nr[r2 * 3 + c2] = s;
      }
    float ntv[3];
    for (int r2 = 0; r2 < 3; ++r2) {
      float s = 0.f;
      for (int k2 = 0; k2 < 3; ++k2) s += nr[r2 * 3 + k2] * ref_t[k2];
      ntv[r2] = -s + feat_t[r2];
    }
    float Ha[9];
    for (int r2 = 0; r2 < 3; ++r2)
      for (int c2 = 0; c2 < 3; ++c2) Ha[r2 * 3 + c2] = nr[c2 * 3 + r2];  // new_r^T
    float u[3];
    for (int r2 = 0; r2 < 3; ++r2) {
      float s = 0.f;
      for (int k2 = 0; k2 < 3; ++k2) s += Ha[r2 * 3 + k2] * ntv[k2];
      u[r2] = s;
    }
    float Hb[9];
    for (int r2 = 0; r2 < 3; ++r2)
      for (int c2 = 0; c2 < 3; ++c2) Hb[r2 * 3 + c2] = u[r2] * Ha[6 + c2];
    float cam[3];
    for (int r2 = 0; r2 < 3; ++r2) {
      float s = 0.f;
      for (int k2 = 0; k2 < 3; ++k2) s += ref_rT[k2 * 3 + r2] * feat_center[k2];
      cam[r2] = s + ref_t[r2];
    }
    for (int j = 0; j < 9; ++j) { sKi[j] = ki[j]; sHa[j] = Ha[j]; sHb[j] = Hb[j]; }
    sHc[0] = u[2];
    for (int j = 0; j < 9; ++j) wsKiCam[j] = ki[j];
    for (int j = 0; j < 3; ++j) wsKiCam[9 + j] = cam[j];
  }
  __syncthreads();
  int p = threadIdx.x;
  if (p < NPLANES) {
    float dnm = -planes[p] - sHc[0];
    float T[9];
    for (int j = 0; j < 9; ++j) T[j] = sHa[j] + sHb[j] / dnm;
    float U[9];
    for (int r2 = 0; r2 < 3; ++r2)
      for (int c2 = 0; c2 < 3; ++c2) {
        float s = 0.f;
        for (int k2 = 0; k2 < 3; ++k2) s += ref_k[r2 * 3 + k2] * T[k2 * 3 + c2];
        U[r2 * 3 + c2] = s;
      }
    for (int r2 = 0; r2 < 3; ++r2)
      for (int c2 = 0; c2 < 3; ++c2) {
        float s = 0.f;
        for (int k2 = 0; k2 < 3; ++k2) s += U[r2 * 3 + k2] * sKi[k2 * 3 + c2];
        wsHs[p * 9 + r2 * 3 + c2] = s;
      }
  }
}

// ---------------------------------------------------------------------------
// pack_all: every weight matrix -> f16 fragment blocks for 16x16x32.
// dst block (kc,t) holds 512 halves [g(4)][ln(16)][j(8)]:
//   value = W[kc*32 + g*8 + j][t*16 + ln]
// ---------------------------------------------------------------------------
__global__ void pack_all_kernel(const float* __restrict__ w0, const float* __restrict__ w1,
                                const float* __restrict__ w2, const float* __restrict__ w3,
                                const float* __restrict__ w4, const float* __restrict__ wo,
                                const float* __restrict__ bw0, const float* __restrict__ bw1,
                                const float* __restrict__ bwo, _Float16* __restrict__ dst)
{
  const int idx = blockIdx.x * 256 + threadIdx.x;
  const float* src; int Ksrc, Nsrc, NP, l;
  if (idx < 24576)       { src = w0;  Ksrc = 56;  Nsrc = 384; NP = 384; l = idx; }
  else if (idx < 172032) { src = w1;  Ksrc = 384; Nsrc = 384; NP = 384; l = idx - 24576; }
  else if (idx < 319488) { src = w2;  Ksrc = 384; Nsrc = 384; NP = 384; l = idx - 172032; }
  else if (idx < 466944) { src = w3;  Ksrc = 384; Nsrc = 384; NP = 384; l = idx - 319488; }
  else if (idx < 614400) { src = w4;  Ksrc = 384; Nsrc = 384; NP = 384; l = idx - 466944; }
  else if (idx < 626688) { src = wo;  Ksrc = 384; Nsrc = 25;  NP = 32;  l = idx - 614400; }
  else if (idx < 628736) { src = bw0; Ksrc = 12;  Nsrc = 64;  NP = 64;  l = idx - 626688; }
  else if (idx < 632832) { src = bw1; Ksrc = 64;  Nsrc = 64;  NP = 64;  l = idx - 628736; }
  else if (idx < 633856) { src = bwo; Ksrc = 64;  Nsrc = 8;   NP = 16;  l = idx - 632832; }
  else return;
  const int within = l & 511, blk = l >> 9;
  const int kg = within >> 7, ln = (within >> 3) & 15, j = within & 7;
  const int ntiles = NP >> 4;
  const int nt = blk % ntiles, kc = blk / ntiles;
  const int k = kc * 32 + kg * 8 + j, nn = nt * 16 + ln;
  const float v = (k < Ksrc && nn < Nsrc) ? src[k * Nsrc + nn] : 0.0f;
  dst[idx] = (_Float16)v;
}

// ---------------------------------------------------------------------------
// main MLP kernel: 64 points per block (one plane), 256 threads = 4 waves.
// Weights = A (m=feature), activations = B (n=point). 16x16x32 MFMA.
// hbuf fragment-ordered; lane reads B-frag at hb[pt*6144 + kc*512 + lane*8].
// ---------------------------------------------------------------------------
template <int NKC>
__device__ __forceinline__ void hidden_layer(_Float16* hb, const _Float16* __restrict__ wl,
                                             const float* __restrict__ bias,
                                             int wv, int g, int ln, int lane)
{
  f32x4 acc[6][4];   // [feature-tile][point-tile]
  #pragma unroll
  for (int ft = 0; ft < 6; ++ft) {
    const f32x4 bv4 = *(const f32x4*)&bias[(wv * 6 + ft) * 16 + g * 4];
    #pragma unroll
    for (int pt = 0; pt < 4; ++pt) acc[ft][pt] = bv4;
  }
  __builtin_amdgcn_s_setprio(1);
  #pragma unroll 2
  for (int kc = 0; kc < NKC; ++kc) {
    half8 aw[6];
    #pragma unroll
    for (int ft = 0; ft < 6; ++ft)
      aw[ft] = *(const half8*)&wl[(kc * 24 + wv * 6 + ft) * 512 + lane * 8];
    half8 bx[4];
    #pragma unroll
    for (int pt = 0; pt < 4; ++pt)
      bx[pt] = *(const half8*)&hb[pt * 6144 + kc * 512 + lane * 8];
    #pragma unroll
    for (int ft = 0; ft < 6; ++ft)
      #pragma unroll
      for (int pt = 0; pt < 4; ++pt)
        acc[ft][pt] = MFMA32(aw[ft], bx[pt], acc[ft][pt]);
  }
  __builtin_amdgcn_s_setprio(0);
  __syncthreads();   // all reads of hb done before overwrite
  #pragma unroll
  for (int pt = 0; pt < 4; ++pt)
    #pragma unroll
    for (int ft = 0; ft < 6; ++ft) {
      const int f0 = wv * 96 + ft * 16 + g * 4;
      *(half4*)&hb[pt * 6144 + (f0 >> 5) * 512 + ((f0 >> 3) & 3) * 128 + ln * 8 + (f0 & 7)] =
          leaky_pack(acc[ft][pt]);
    }
  __syncthreads();
}

// basis layer: ping-pong through disjoint LDS col regions; no internal
// barriers (read region and write region never overlap).
// Reads cols [src_kc*32, src_kc*32+NKC*32), writes features dstC + wv*16+g*4.
template <int NKC>
__device__ __forceinline__ void basis_hidden(_Float16* hb, const _Float16* __restrict__ wl,
                                             const float* __restrict__ bias,
                                             int src_kc, int dstC,
                                             int wv, int g, int ln, int lane)
{
  f32x4 acc[4];      // [point-tile], this wave owns feature-tile wv
  const f32x4 bv4 = *(const f32x4*)&bias[wv * 16 + g * 4];
  #pragma unroll
  for (int pt = 0; pt < 4; ++pt) acc[pt] = bv4;
  __builtin_amdgcn_s_setprio(1);
  #pragma unroll
  for (int kc = 0; kc < NKC; ++kc) {
    half8 aw = *(const half8*)&wl[(kc * 4 + wv) * 512 + lane * 8];
    #pragma unroll
    for (int pt = 0; pt < 4; ++pt) {
      half8 bx = *(const half8*)&hb[pt * 6144 + (src_kc + kc) * 512 + lane * 8];
      acc[pt] = MFMA32(aw, bx, acc[pt]);
    }
  }
  __builtin_amdgcn_s_setprio(0);
  const int f0 = dstC + wv * 16 + g * 4;
  #pragma unroll
  for (int pt = 0; pt < 4; ++pt)
    *(half4*)&hb[pt * 6144 + (f0 >> 5) * 512 + ((f0 >> 3) & 3) * 128 + ln * 8 + (f0 & 7)] =
        leaky_pack(acc[pt]);
}

__global__ __launch_bounds__(256, 3) void mlp_kernel(
    const int* __restrict__ selection, const float* __restrict__ planes,
    const float* __restrict__ wsHs, const float* __restrict__ wsKiCam,
    const _Float16* __restrict__ pw0, const _Float16* __restrict__ pw1,
    const _Float16* __restrict__ pw2, const _Float16* __restrict__ pw3,
    const _Float16* __restrict__ pw4, const _Float16* __restrict__ pwo,
    const float* __restrict__ b0, const float* __restrict__ b1,
    const float* __restrict__ b2, const float* __restrict__ b3,
    const float* __restrict__ b4, const float* __restrict__ bo,
    const _Float16* __restrict__ pbw0, const _Float16* __restrict__ pbw1,
    const _Float16* __restrict__ pbwo,
    const float* __restrict__ bb0, const float* __restrict__ bb1,
    const float* __restrict__ bbo,
    float* __restrict__ wsAlpha, float* __restrict__ wsCoeff, float* __restrict__ wsBasis)
{
  __shared__ _Float16 hbuf[4 * 6144];   // 49152 B, fragment-ordered
  const int t = threadIdx.x;
  const int m0 = blockIdx.x * 64;
  const int p = m0 >> 10;       // plane (blocks never straddle planes: 16 blocks/plane)
  const int r0 = m0 & 1023;
  const int lane = t & 63, wv = t >> 6;
  const int g = lane >> 4, ln = lane & 15;

  // ---- phase 1: positional encoding -> cols 0..63 (56 real + 8 zero pad) ----
  {
    const int i = t >> 2, q = t & 3;   // 4 threads per point
    const int ray = r0 + i;
    const int sel = selection[ray];
    const float cx = (float)(sel % IMW), cy = (float)(sel / IMW);
    const float* H = wsHs + p * 9;
    const float pr0 = H[0] * cx + H[1] * cy + H[2];
    const float pr1 = H[3] * cx + H[4] * cy + H[5];
    const float pr2 = H[6] * cx + H[7] * cy + H[8];
    const float rx = pr0 / pr2, ry = pr1 / pr2;
    const float wx = (rx / 767.0f) * 2.0f - 1.0f;
    const float wy = (ry / 511.0f) * 2.0f - 1.0f;
    const float zc = -1.0f + (float)p * (2.0f / 191.0f);
    // sin(base * pi/2 * 2^c) = sin_rev(base * 2^(c-2)); cos = sin_rev(+0.25)
    #pragma unroll
    for (int cc = 0; cc < 7; ++cc) {
      const int c = q * 7 + cc;
      float base; int e;
      if (c < 10)      { base = wx; e = c; }
      else if (c < 20) { base = wy; e = c - 10; }
      else             { base = zc; e = c - 20; }
      const float rev = ldexpf(base, e - 2);
      hbuf[FR(i, c)]      = (_Float16)sin_rev(rev);
      hbuf[FR(i, c + 28)] = (_Float16)sin_rev(rev + 0.25f);
    }
    hbuf[FR(i, 56 + q)] = (_Float16)0.f;
    hbuf[FR(i, 60 + q)] = (_Float16)0.f;
  }
  __syncthreads();

  // ---- main MLP ----
  hidden_layer<2>(hbuf, pw0, b0, wv, g, ln, lane);
  hidden_layer<12>(hbuf, pw1, b1, wv, g, ln, lane);
  hidden_layer<12>(hbuf, pw2, b2, wv, g, ln, lane);
  hidden_layer<12>(hbuf, pw3, b3, wv, g, ln, lane);
  hidden_layer<12>(hbuf, pw4, b4, wv, g, ln, lane);

  // ---- output layer (25 features padded to 32 = 2 ft-tiles), wave owns pt=wv ----
  f32x4 acc2[2];
  {
    #pragma unroll
    for (int ft = 0; ft < 2; ++ft) {
      f32x4 bv;
      #pragma unroll
      for (int r = 0; r < 4; ++r) {
        const int f = ft * 16 + g * 4 + r;
        bv[r] = (f < 25) ? bo[f] : 0.f;
      }
      acc2[ft] = bv;
    }
    __builtin_amdgcn_s_setprio(1);
    #pragma unroll 2
    for (int kc = 0; kc < 12; ++kc) {
      half8 bx = *(const half8*)&hbuf[wv * 6144 + kc * 512 + lane * 8];
      #pragma unroll
      for (int ft = 0; ft < 2; ++ft) {
        half8 aw = *(const half8*)&pwo[(kc * 2 + ft) * 512 + lane * 8];
        acc2[ft] = MFMA32(aw, bx, acc2[ft]);
      }
    }
    __builtin_amdgcn_s_setprio(0);
    __syncthreads();   // all hbuf reads done
  }

  // ---- view-direction encoding -> cols 0..15 (12 real + 4 zero pad) ----
  {
    const int i = t >> 2, q = t & 3;
    const int ray = r0 + i;
    const int sel = selection[ray];
    const float cx = (float)(sel % IMW), cy = (float)(sel / IMW);
    const float* H = wsHs + p * 9;
    const float pr0 = H[0] * cx + H[1] * cy + H[2];
    const float pr1 = H[3] * cx + H[4] * cy + H[5];
    const float pr2 = H[6] * cx + H[7] * cy + H[8];
    const float rx = pr0 / pr2, ry = pr1 / pr2;
    const float pd = planes[p];
    const float* ki = wsKiCam; const float* cam = wsKiCam + 9;
    const float c0 = rx * pd, c1 = ry * pd, c2 = pd;
    const float vx0 = ki[0] * c0 + ki[1] * c1 + ki[2] * c2 - cam[0];
    const float vy0 = ki[3] * c0 + ki[4] * c1 + ki[5] * c2 - cam[1];
    const float vz0 = ki[6] * c0 + ki[7] * c1 + ki[8] * c2 - cam[2];
    const float nrm = sqrtf(vx0 * vx0 + vy0 * vy0 + vz0 * vz0) + 1e-7f;
    const float vx = vx0 / nrm, vy = vy0 / nrm;
    // sin(pi/2 * v * 2^e) = sin_rev(v * 2^(e-2))
    #pragma unroll
    for (int cc = 0; cc < 4; ++cc) {
      const int c = q * 4 + cc;
      float v;
      if (c < 6) {
        v = sin_rev(ldexpf((c < 3) ? vx : vy, (c % 3) - 2));
      } else if (c < 12) {
        const int c6 = c - 6;
        v = sin_rev(ldexpf((c6 < 3) ? vx : vy, (c6 % 3) - 2) + 0.25f);
      } else v = 0.f;
      hbuf[FR(i, c)] = (_Float16)v;
    }
  }
  __syncthreads();   // venc visible to all waves

  // ---- alpha / coeff epilogue from output-layer registers (plane-major) ----
  // (global stores only; overlaps with basis MFMA below — no barrier needed)
  {
    if (g == 0) {   // feature 0 lives in reg r=0 of g=0, ft=0
      const int ray = r0 + wv * 16 + ln;
      wsAlpha[p * RAYS + ray] = sig5_fast(acc2[0][0]);
    }
    if ((p % 12) == 0) {
      const int pg = p / 12;
      const int ray = r0 + wv * 16 + ln;
      #pragma unroll
      for (int ft = 0; ft < 2; ++ft)
        #pragma unroll
        for (int r = 0; r < 4; ++r) {
          const int f = ft * 16 + g * 4 + r;
          if (f >= 1 && f < 25)
            wsCoeff[(pg * 24 + (f - 1)) * RAYS + ray] = tanh_fast(acc2[ft][r]);
        }
    }
  }

  // ---- basis MLP ping-pong: venc(cols0-31) -> 64-127 -> 128-191 -> out ----
  basis_hidden<1>(hbuf, pbw0, bb0, 0, 64, wv, g, ln, lane);
  __syncthreads();
  basis_hidden<2>(hbuf, pbw1, bb1, 2, 128, wv, g, ln, lane);
  __syncthreads();
  {
    f32x4 accO = (f32x4){0.f, 0.f, 0.f, 0.f};
    #pragma unroll
    for (int kc = 0; kc < 2; ++kc) {
      half8 aw = *(const half8*)&pbwo[kc * 512 + lane * 8];
      half8 bx = *(const half8*)&hbuf[wv * 6144 + (4 + kc) * 512 + lane * 8];
      accO = MFMA32(aw, bx, accO);
    }
    if (g < 2) {   // features 0..7; one float4 store per lane, 512B/wave span
      const int ray = r0 + wv * 16 + ln;
      f32x4 bv;
      #pragma unroll
      for (int r = 0; r < 4; ++r)
        bv[r] = tanh_fast(accO[r] + bbo[g * 4 + r]);
      *(f32x4*)&wsBasis[(p * RAYS + ray) * 8 + g * 4] = bv;
    }
  }
}

// ---------------------------------------------------------------------------
// composite: per ray (block, 192 threads = 1 thread/plane):
// grid-sample sigmoid(mpi), illum = coeff . basis, clip, prefix-product scan,
// weighted sum -> out[3][1024]
// ---------------------------------------------------------------------------
__global__ __launch_bounds__(192) void composite_kernel(
    const float* __restrict__ mpi, const int* __restrict__ selection,
    const float* __restrict__ wsHs, const float* __restrict__ wsAlpha,
    const float* __restrict__ wsCoeff, const float* __restrict__ wsBasis,
    float* __restrict__ out)
{
  const int ray = blockIdx.x;
  const int p = threadIdx.x;
  const int sel = selection[ray];
  const float cx = (float)(sel % IMW), cy = (float)(sel / IMW);
  const float* H = wsHs + p * 9;
  const float pr0 = H[0] * cx + H[1] * cy + H[2];
  const float pr1 = H[3] * cx + H[4] * cy + H[5];
  const float pr2 = H[6] * cx + H[7] * cy + H[8];
  const float rx = pr0 / pr2, ry = pr1 / pr2;
  const float wx = (rx / 767.0f) * 2.0f - 1.0f;
  const float wy = (ry / 511.0f) * 2.0f - 1.0f;
  const float x = (wx + 1.0f) * 0.5f * 767.0f;
  const float y = (wy + 1.0f) * 0.5f * 511.0f;
  const float gz = -1.0f + (float)(p / 12) * (2.0f / 15.0f);
  const float z = (gz + 1.0f) * 0.5f * 15.0f;
  const float x0 = floorf(x), y0 = floorf(y), z0 = floorf(z);
  float rgb0 = 0.f, rgb1 = 0.f, rgb2 = 0.f;
  #pragma unroll
  for (int dz = 0; dz < 2; ++dz)
    #pragma unroll
    for (int dy = 0; dy < 2; ++dy)
      #pragma unroll
      for (int dx = 0; dx < 2; ++dx) {
        const float xi = x0 + (float)dx, yi = y0 + (float)dy, zi = z0 + (float)dz;
        const float w = (1.f - fabsf(x - xi)) * (1.f - fabsf(y - yi)) * (1.f - fabsf(z - zi));
        const bool valid = (xi >= 0.f) && (xi < 768.f) && (yi >= 0.f) && (yi < 512.f)
                        && (zi >= 0.f) && (zi < 16.f);
        if (valid && w != 0.f) {
          const int ix = (int)xi, iy = (int)yi, iz = (int)zi;
          const int base = iz * 3 * (IMW * IMH) + iy * IMW + ix;   // mpi[d][c][y][x]
          const float v0 = mpi[base];
          const float v1 = mpi[base + IMW * IMH];
          const float v2 = mpi[base + 2 * IMW * IMH];
          rgb0 += w * (1.f / (1.f + expf(-v0)));
          rgb1 += w * (1.f / (1.f + expf(-v1)));
          rgb2 += w * (1.f / (1.f + expf(-v2)));
        }
      }
  const float* bs = wsBasis + (p * RAYS + ray) * 8;
  const float* cf = wsCoeff + (p / 12) * 24 * RAYS + ray;
  float il0 = 0.f, il1 = 0.f, il2 = 0.f;
  #pragma unroll
  for (int j = 0; j < 8; ++j) {
    const float bj = bs[j];
    il0 += cf[j * RAYS] * bj;
    il1 += cf[(8 + j) * RAYS] * bj;
    il2 += cf[(16 + j) * RAYS] * bj;
  }
  rgb0 = fminf(fmaxf(rgb0 + il0, 0.f), 1.f);
  rgb1 = fminf(fmaxf(rgb1 + il1, 0.f), 1.f);
  rgb2 = fminf(fmaxf(rgb2 + il2, 0.f), 1.f);
  const float a = wsAlpha[p * RAYS + ray];
  const int lane = p & 63, w64 = p >> 6;
  // inclusive prefix product of (1-a) within each wave
  float xs = 1.f - a;
  #pragma unroll
  for (int off = 1; off < 64; off <<= 1) {
    const float v = __shfl_up(xs, off, 64);
    if (lane >= off) xs *= v;
  }
  __shared__ float wtot[3];
  __shared__ float part[3][3];
  if (lane == 63) wtot[w64] = xs;
  __syncthreads();
  float pre = 1.f;
  #pragma unroll
  for (int q = 0; q < 2; ++q)
    if (q < w64) pre *= wtot[q];
  float excl = __shfl_up(xs, 1, 64);
  if (lane == 0) excl = 1.f;
  const float wa = pre * excl * a;
  float s0 = wa * rgb0, s1 = wa * rgb1, s2 = wa * rgb2;
  #pragma unroll
  for (int off = 32; off >= 1; off >>= 1) {
    s0 += __shfl_down(s0, off, 64);
    s1 += __shfl_down(s1, off, 64);
    s2 += __shfl_down(s2, off, 64);
  }
  if (lane == 0) { part[w64][0] = s0; part[w64][1] = s1; part[w64][2] = s2; }
  __syncthreads();
  if (p == 0) {
    out[0 * RAYS + ray] = part[0][0] + part[1][0] + part[2][0];
    out[1 * RAYS + ray] = part[0][1] + part[1][1] + part[2][1];
    out[2 * RAYS + ray] = part[0][2] + part[1][2] + part[2][2];
  }
}

// ---------------------------------------------------------------------------
extern "C" void kernel_launch(void* const* d_in, const int* in_sizes, int n_in,
                              void* d_out, int out_size, void* d_ws, size_t ws_size,
                              hipStream_t stream)
{
  (void)in_sizes; (void)n_in; (void)out_size;
  const float* mpi    = (const float*)d_in[0];
  const float* w0     = (const float*)d_in[1];
  const float* b0     = (const float*)d_in[2];
  const float* w1     = (const float*)d_in[3];
  const float* b1     = (const float*)d_in[4];
  const float* w2     = (const float*)d_in[5];
  const float* b2     = (const float*)d_in[6];
  const float* w3     = (const float*)d_in[7];
  const float* b3     = (const float*)d_in[8];
  const float* w4     = (const float*)d_in[9];
  const float* b4     = (const float*)d_in[10];
  const float* wo     = (const float*)d_in[11];
  const float* bo     = (const float*)d_in[12];
  const float* bw0    = (const float*)d_in[13];
  const float* bb0    = (const float*)d_in[14];
  const float* bw1    = (const float*)d_in[15];
  const float* bb1    = (const float*)d_in[16];
  const float* bwo    = (const float*)d_in[17];
  const float* bbo    = (const float*)d_in[18];
  const float* ref_rT = (const float*)d_in[19];
  const float* ref_t  = (const float*)d_in[20];
  const float* ref_k  = (const float*)d_in[21];
  const float* feat_r = (const float*)d_in[22];
  const float* feat_t = (const float*)d_in[23];
  const float* feat_c = (const float*)d_in[24];
  const float* feat_k = (const float*)d_in[25];
  const float* planes = (const float*)d_in[26];
  const int*   selection = (const int*)d_in[27];
  float* outp = (float*)d_out;
  char* ws = (char*)d_ws;
  if (ws_size < (size_t)WS_NEED) return;   // workspace too small -> visible failure

  float* wsHs    = (float*)(ws + O_HS);
  float* wsKiCam = (float*)(ws + O_KICAM);
  float* wsAlpha = (float*)(ws + O_ALPHA);
  float* wsCoeff = (float*)(ws + O_COEFF);
  float* wsBasis = (float*)(ws + O_BASIS);
  _Float16* pw0  = (_Float16*)(ws + O_PW0);
  _Float16* pw1  = (_Float16*)(ws + O_PW1);
  _Float16* pw2  = (_Float16*)(ws + O_PW2);
  _Float16* pw3  = (_Float16*)(ws + O_PW3);
  _Float16* pw4  = (_Float16*)(ws + O_PW4);
  _Float16* pwo  = (_Float16*)(ws + O_PWO);
  _Float16* pbw0 = (_Float16*)(ws + O_PBW0);
  _Float16* pbw1 = (_Float16*)(ws + O_PBW1);
  _Float16* pbwo = (_Float16*)(ws + O_PBWO);

  prep_kernel<<<1, 256, 0, stream>>>(ref_rT, ref_t, ref_k, feat_r, feat_t, feat_c,
                                     feat_k, planes, wsHs, wsKiCam);
  pack_all_kernel<<<2476, 256, 0, stream>>>(w0, w1, w2, w3, w4, wo, bw0, bw1, bwo, pw0);

  mlp_kernel<<<(NPLANES * RAYS) / 64, 256, 0, stream>>>(
      selection, planes, wsHs, wsKiCam,
      pw0, pw1, pw2, pw3, pw4, pwo,
      b0, b1, b2, b3, b4, bo,
      pbw0, pbw1, pbwo, bb0, bb1, bbo,
      wsAlpha, wsCoeff, wsBasis);

  composite_kernel<<<RAYS, NPLANES, 0, stream>>>(mpi, selection, wsHs, wsAlpha,
                                                 wsCoeff, wsBasis, outp);
}

// Round 14
// 254.827 us; speedup vs baseline: 1.6065x; 1.0139x over previous
//
#include <hip/hip_runtime.h>
#include <hip/hip_bf16.h>
#include <math.h>

// ---------------------------------------------------------------------------
// MPI-NeRF style network renderer for MI355X (gfx950).
// R13: R12 (258us) with prep_kernel fused into pack_all block 0 (one launch
//      saved). mlp_kernel and composite_kernel byte-identical to R12.
// ---------------------------------------------------------------------------

typedef _Float16 half2 __attribute__((ext_vector_type(2)));
typedef _Float16 half4 __attribute__((ext_vector_type(4)));
typedef _Float16 half8 __attribute__((ext_vector_type(8)));
typedef float f32x4 __attribute__((ext_vector_type(4)));

#if __has_builtin(__builtin_amdgcn_mfma_f32_16x16x32_f16)
#define MFMA32(a, b, c) __builtin_amdgcn_mfma_f32_16x16x32_f16((a), (b), (c), 0, 0, 0)
#else
#define MFMA32(a, b, c) (c)   // host-pass placeholder (never executed)
#endif

#define NPLANES 192
#define RAYS    1024
#define IMW     768
#define IMH     512

// fragment-order index into hbuf: point i (0..63), feature/column c (0..383)
// layout [pt(4)][kc(12)][g(4)][ln(16)][j(8)], strides 6144/512/128/8/1 halves
#define FR(i, c) ((((i) >> 4) * 6144) + (((c) >> 5) * 512) + ((((c) >> 3) & 3) * 128) \
                  + (((i) & 15) * 8) + ((c) & 7))

// sin(2*pi*rev) via HW: fract to [0,1) then v_sin
__device__ __forceinline__ float sin_rev(float rev) {
  float f, r;
  asm("v_fract_f32 %0, %1" : "=v"(f) : "v"(rev));
  asm("v_sin_f32 %0, %1" : "=v"(r) : "v"(f));
  return r;
}
__device__ __forceinline__ float exp2_fast(float x) {
  float r;
  asm("v_exp_f32 %0, %1" : "=v"(r) : "v"(x));
  return r;
}
__device__ __forceinline__ float rcp_fast(float x) {
  float r;
  asm("v_rcp_f32 %0, %1" : "=v"(r) : "v"(x));
  return r;
}
__device__ __forceinline__ float tanh_fast(float x) {
  const float xc = fminf(fmaxf(x, -30.f), 30.f);
  const float t = exp2_fast(xc * 2.885390082f);   // 2*log2(e)
  return (t - 1.f) * rcp_fast(t + 1.f);
}
__device__ __forceinline__ float sig5_fast(float o) {
  const float u = exp2_fast((5.f - o) * 1.4426950f);
  return rcp_fast(1.f + u);
}

// packed f32x4 -> f16x4 (RTZ), then leaky in packed f16:
// max(h, 0.01*h) picks h for h>=0 and 0.01h for h<0.
__device__ __forceinline__ half4 leaky_pack(f32x4 a) {
  const half2 lo = __builtin_bit_cast(half2, __builtin_amdgcn_cvt_pkrtz(a[0], a[1]));
  const half2 hi = __builtin_bit_cast(half2, __builtin_amdgcn_cvt_pkrtz(a[2], a[3]));
  half4 h = __builtin_shufflevector(lo, hi, 0, 1, 2, 3);
  half4 s = h * (_Float16)0.01f;
#if __has_builtin(__builtin_elementwise_max)
  return __builtin_elementwise_max(h, s);
#else
  half4 r;
  #pragma unroll
  for (int k = 0; k < 4; ++k) r[k] = (h[k] >= s[k]) ? h[k] : s[k];
  return r;
#endif
}

// ---- workspace layout (bytes), all offsets 256-aligned ----
// Side outputs PLANE-MAJOR: alpha[p][ray], basis[p][ray][8], coeff[pg][24][ray]
#define O_HS     0           // Hs[192][9] f32                     (6912)
#define O_KICAM  7168        // ki[9], cam[3] f32                  (48)
#define O_ALPHA  7424        // alpha[p][ray] f32                  (786432)
#define O_COEFF  793856      // coeff[pg][24][ray] f32             (1572864)
#define O_PW0    2366720     // packed weights, contiguous (see pack_all)
#define O_PW1    2415872
#define O_PW2    2710784
#define O_PW3    3005696
#define O_PW4    3300608
#define O_PWO    3595520
#define O_PBW0   3620096
#define O_PBW1   3624192
#define O_PBWO   3632384
#define O_BASIS  3634432     // basis[p][ray][8] f32               (6291456)
#define WS_NEED  (O_BASIS + 6291456)

// ---------------------------------------------------------------------------
// pack_all (+fused prep in block 0): weights -> f16 fragment blocks for
// 16x16x32. dst block (kc,t) holds 512 halves [g(4)][ln(16)][j(8)]:
//   value = W[kc*32 + g*8 + j][t*16 + ln]
// Block 0's 256 threads all fall in the w0 segment (idx 0..255 < 24576), so
// no early return -> the prep barriers below are block-uniform and safe.
// ---------------------------------------------------------------------------
__global__ void pack_all_kernel(const float* __restrict__ w0, const float* __restrict__ w1,
                                const float* __restrict__ w2, const float* __restrict__ w3,
                                const float* __restrict__ w4, const float* __restrict__ wo,
                                const float* __restrict__ bw0, const float* __restrict__ bw1,
                                const float* __restrict__ bwo, _Float16* __restrict__ dst,
                                const float* __restrict__ ref_rT, const float* __restrict__ ref_t,
                                const float* __restrict__ ref_k, const float* __restrict__ feat_r,
                                const float* __restrict__ feat_t, const float* __restrict__ feat_center,
                                const float* __restrict__ feat_k, const float* __restrict__ planes,
                                float* __restrict__ wsHs, float* __restrict__ wsKiCam)
{
  const int idx = blockIdx.x * 256 + threadIdx.x;
  {
    const float* src; int Ksrc, Nsrc, NP, l;
    bool ok = true;
    if (idx < 24576)       { src = w0;  Ksrc = 56;  Nsrc = 384; NP = 384; l = idx; }
    else if (idx < 172032) { src = w1;  Ksrc = 384; Nsrc = 384; NP = 384; l = idx - 24576; }
    else if (idx < 319488) { src = w2;  Ksrc = 384; Nsrc = 384; NP = 384; l = idx - 172032; }
    else if (idx < 466944) { src = w3;  Ksrc = 384; Nsrc = 384; NP = 384; l = idx - 319488; }
    else if (idx < 614400) { src = w4;  Ksrc = 384; Nsrc = 384; NP = 384; l = idx - 466944; }
    else if (idx < 626688) { src = wo;  Ksrc = 384; Nsrc = 25;  NP = 32;  l = idx - 614400; }
    else if (idx < 628736) { src = bw0; Ksrc = 12;  Nsrc = 64;  NP = 64;  l = idx - 626688; }
    else if (idx < 632832) { src = bw1; Ksrc = 64;  Nsrc = 64;  NP = 64;  l = idx - 628736; }
    else if (idx < 633856) { src = bwo; Ksrc = 64;  Nsrc = 8;   NP = 16;  l = idx - 632832; }
    else { ok = false; src = w0; Ksrc = 0; Nsrc = 0; NP = 16; l = 0; }
    if (ok) {
      const int within = l & 511, blk = l >> 9;
      const int kg = within >> 7, ln = (within >> 3) & 15, j = within & 7;
      const int ntiles = NP >> 4;
      const int nt = blk % ntiles, kc = blk / ntiles;
      const int k = kc * 32 + kg * 8 + j, nn = nt * 16 + ln;
      const float v = (k < Ksrc && nn < Nsrc) ? src[k * Nsrc + nn] : 0.0f;
      dst[idx] = (_Float16)v;
    }
  }

  if (blockIdx.x != 0) return;
  // ---- fused prep: homographies Hs[p], ki, camera (block 0 only) ----
  __shared__ float sKi[9], sHa[9], sHb[9], sHc[1];
  if (threadIdx.x == 0) {
    float a = feat_k[0], b = feat_k[1], c = feat_k[2];
    float d = feat_k[3], e = feat_k[4], f = feat_k[5];
    float g = feat_k[6], h = feat_k[7], i = feat_k[8];
    float A = e * i - f * h, B = -(d * i - f * g), C = d * h - e * g;
    float det = a * A + b * B + c * C;
    float id = 1.0f / det;
    float ki[9];
    ki[0] = A * id;             ki[1] = -(b * i - c * h) * id;  ki[2] = (b * f - c * e) * id;
    ki[3] = B * id;             ki[4] = (a * i - c * g) * id;   ki[5] = -(a * f - c * d) * id;
    ki[6] = C * id;             ki[7] = -(a * h - b * g) * id;  ki[8] = (a * e - b * d) * id;
    float nr[9];
    for (int r2 = 0; r2 < 3; ++r2)
      for (int c2 = 0; c2 < 3; ++c2) {
        float s = 0.f;
        for (int k2 = 0; k2 < 3; ++k2) s += feat_r[r2 * 3 + k2] * ref_rT[k2 * 3 + c2];
        nr[r2 * 3 + c2] = s;
      }
    float ntv[3];
    for (int r2 = 0; r2 < 3; ++r2) {
      float s = 0.f;
      for (int k2 = 0; k2 < 3; ++k2) s += nr[r2 * 3 + k2] * ref_t[k2];
      ntv[r2] = -s + feat_t[r2];
    }
    float Ha[9];
    for (int r2 = 0; r2 < 3; ++r2)
      for (int c2 = 0; c2 < 3; ++c2) Ha[r2 * 3 + c2] = nr[c2 * 3 + r2];  // new_r^T
    float u[3];
    for (int r2 = 0; r2 < 3; ++r2) {
      float s = 0.f;
      for (int k2 = 0; k2 < 3; ++k2) s += Ha[r2 * 3 + k2] * ntv[k2];
      u[r2] = s;
    }
    float Hb[9];
    for (int r2 = 0; r2 < 3; ++r2)
      for (int c2 = 0; c2 < 3; ++c2) Hb[r2 * 3 + c2] = u[r2] * Ha[6 + c2];
    float cam[3];
    for (int r2 = 0; r2 < 3; ++r2) {
      float s = 0.f;
      for (int k2 = 0; k2 < 3; ++k2) s += ref_rT[k2 * 3 + r2] * feat_center[k2];
      cam[r2] = s + ref_t[r2];
    }
    for (int j = 0; j < 9; ++j) { sKi[j] = ki[j]; sHa[j] = Ha[j]; sHb[j] = Hb[j]; }
    sHc[0] = u[2];
    for (int j = 0; j < 9; ++j) wsKiCam[j] = ki[j];
    for (int j = 0; j < 3; ++j) wsKiCam[9 + j] = cam[j];
  }
  __syncthreads();
  const int p = threadIdx.x;
  if (p < NPLANES) {
    float dnm = -planes[p] - sHc[0];
    float T[9];
    for (int j = 0; j < 9; ++j) T[j] = sHa[j] + sHb[j] / dnm;
    float U[9];
    for (int r2 = 0; r2 < 3; ++r2)
      for (int c2 = 0; c2 < 3; ++c2) {
        float s = 0.f;
        for (int k2 = 0; k2 < 3; ++k2) s += ref_k[r2 * 3 + k2] * T[k2 * 3 + c2];
        U[r2 * 3 + c2] = s;
      }
    for (int r2 = 0; r2 < 3; ++r2)
      for (int c2 = 0; c2 < 3; ++c2) {
        float s = 0.f;
        for (int k2 = 0; k2 < 3; ++k2) s += U[r2 * 3 + k2] * sKi[k2 * 3 + c2];
        wsHs[p * 9 + r2 * 3 + c2] = s;
      }
  }
}

// ---------------------------------------------------------------------------
// main MLP kernel: 64 points per block (one plane), 256 threads = 4 waves.
// Weights = A (m=feature), activations = B (n=point). 16x16x32 MFMA.
// hbuf fragment-ordered; lane reads B-frag at hb[pt*6144 + kc*512 + lane*8].
// ---------------------------------------------------------------------------
template <int NKC>
__device__ __forceinline__ void hidden_layer(_Float16* hb, const _Float16* __restrict__ wl,
                                             const float* __restrict__ bias,
                                             int wv, int g, int ln, int lane)
{
  f32x4 acc[6][4];   // [feature-tile][point-tile]
  #pragma unroll
  for (int ft = 0; ft < 6; ++ft) {
    const f32x4 bv4 = *(const f32x4*)&bias[(wv * 6 + ft) * 16 + g * 4];
    #pragma unroll
    for (int pt = 0; pt < 4; ++pt) acc[ft][pt] = bv4;
  }
  __builtin_amdgcn_s_setprio(1);
  #pragma unroll 2
  for (int kc = 0; kc < NKC; ++kc) {
    half8 aw[6];
    #pragma unroll
    for (int ft = 0; ft < 6; ++ft)
      aw[ft] = *(const half8*)&wl[(kc * 24 + wv * 6 + ft) * 512 + lane * 8];
    half8 bx[4];
    #pragma unroll
    for (int pt = 0; pt < 4; ++pt)
      bx[pt] = *(const half8*)&hb[pt * 6144 + kc * 512 + lane * 8];
    #pragma unroll
    for (int ft = 0; ft < 6; ++ft)
      #pragma unroll
      for (int pt = 0; pt < 4; ++pt)
        acc[ft][pt] = MFMA32(aw[ft], bx[pt], acc[ft][pt]);
  }
  __builtin_amdgcn_s_setprio(0);
  __syncthreads();   // all reads of hb done before overwrite
  #pragma unroll
  for (int pt = 0; pt < 4; ++pt)
    #pragma unroll
    for (int ft = 0; ft < 6; ++ft) {
      const int f0 = wv * 96 + ft * 16 + g * 4;
      *(half4*)&hb[pt * 6144 + (f0 >> 5) * 512 + ((f0 >> 3) & 3) * 128 + ln * 8 + (f0 & 7)] =
          leaky_pack(acc[ft][pt]);
    }
  __syncthreads();
}

// basis layer: ping-pong through disjoint LDS col regions; no internal
// barriers (read region and write region never overlap).
// Reads cols [src_kc*32, src_kc*32+NKC*32), writes features dstC + wv*16+g*4.
template <int NKC>
__device__ __forceinline__ void basis_hidden(_Float16* hb, const _Float16* __restrict__ wl,
                                             const float* __restrict__ bias,
                                             int src_kc, int dstC,
                                             int wv, int g, int ln, int lane)
{
  f32x4 acc[4];      // [point-tile], this wave owns feature-tile wv
  const f32x4 bv4 = *(const f32x4*)&bias[wv * 16 + g * 4];
  #pragma unroll
  for (int pt = 0; pt < 4; ++pt) acc[pt] = bv4;
  __builtin_amdgcn_s_setprio(1);
  #pragma unroll
  for (int kc = 0; kc < NKC; ++kc) {
    half8 aw = *(const half8*)&wl[(kc * 4 + wv) * 512 + lane * 8];
    #pragma unroll
    for (int pt = 0; pt < 4; ++pt) {
      half8 bx = *(const half8*)&hb[pt * 6144 + (src_kc + kc) * 512 + lane * 8];
      acc[pt] = MFMA32(aw, bx, acc[pt]);
    }
  }
  __builtin_amdgcn_s_setprio(0);
  const int f0 = dstC + wv * 16 + g * 4;
  #pragma unroll
  for (int pt = 0; pt < 4; ++pt)
    *(half4*)&hb[pt * 6144 + (f0 >> 5) * 512 + ((f0 >> 3) & 3) * 128 + ln * 8 + (f0 & 7)] =
        leaky_pack(acc[pt]);
}

__global__ __launch_bounds__(256, 3) void mlp_kernel(
    const int* __restrict__ selection, const float* __restrict__ planes,
    const float* __restrict__ wsHs, const float* __restrict__ wsKiCam,
    const _Float16* __restrict__ pw0, const _Float16* __restrict__ pw1,
    const _Float16* __restrict__ pw2, const _Float16* __restrict__ pw3,
    const _Float16* __restrict__ pw4, const _Float16* __restrict__ pwo,
    const float* __restrict__ b0, const float* __restrict__ b1,
    const float* __restrict__ b2, const float* __restrict__ b3,
    const float* __restrict__ b4, const float* __restrict__ bo,
    const _Float16* __restrict__ pbw0, const _Float16* __restrict__ pbw1,
    const _Float16* __restrict__ pbwo,
    const float* __restrict__ bb0, const float* __restrict__ bb1,
    const float* __restrict__ bbo,
    float* __restrict__ wsAlpha, float* __restrict__ wsCoeff, float* __restrict__ wsBasis)
{
  __shared__ _Float16 hbuf[4 * 6144];   // 49152 B, fragment-ordered
  const int t = threadIdx.x;
  const int m0 = blockIdx.x * 64;
  const int p = m0 >> 10;       // plane (blocks never straddle planes: 16 blocks/plane)
  const int r0 = m0 & 1023;
  const int lane = t & 63, wv = t >> 6;
  const int g = lane >> 4, ln = lane & 15;

  // ---- phase 1: positional encoding -> cols 0..63 (56 real + 8 zero pad) ----
  {
    const int i = t >> 2, q = t & 3;   // 4 threads per point
    const int ray = r0 + i;
    const int sel = selection[ray];
    const float cx = (float)(sel % IMW), cy = (float)(sel / IMW);
    const float* H = wsHs + p * 9;
    const float pr0 = H[0] * cx + H[1] * cy + H[2];
    const float pr1 = H[3] * cx + H[4] * cy + H[5];
    const float pr2 = H[6] * cx + H[7] * cy + H[8];
    const float rx = pr0 / pr2, ry = pr1 / pr2;
    const float wx = (rx / 767.0f) * 2.0f - 1.0f;
    const float wy = (ry / 511.0f) * 2.0f - 1.0f;
    const float zc = -1.0f + (float)p * (2.0f / 191.0f);
    // sin(base * pi/2 * 2^c) = sin_rev(base * 2^(c-2)); cos = sin_rev(+0.25)
    #pragma unroll
    for (int cc = 0; cc < 7; ++cc) {
      const int c = q * 7 + cc;
      float base; int e;
      if (c < 10)      { base = wx; e = c; }
      else if (c < 20) { base = wy; e = c - 10; }
      else             { base = zc; e = c - 20; }
      const float rev = ldexpf(base, e - 2);
      hbuf[FR(i, c)]      = (_Float16)sin_rev(rev);
      hbuf[FR(i, c + 28)] = (_Float16)sin_rev(rev + 0.25f);
    }
    hbuf[FR(i, 56 + q)] = (_Float16)0.f;
    hbuf[FR(i, 60 + q)] = (_Float16)0.f;
  }
  __syncthreads();

  // ---- main MLP ----
  hidden_layer<2>(hbuf, pw0, b0, wv, g, ln, lane);
  hidden_layer<12>(hbuf, pw1, b1, wv, g, ln, lane);
  hidden_layer<12>(hbuf, pw2, b2, wv, g, ln, lane);
  hidden_layer<12>(hbuf, pw3, b3, wv, g, ln, lane);
  hidden_layer<12>(hbuf, pw4, b4, wv, g, ln, lane);

  // ---- output layer (25 features padded to 32 = 2 ft-tiles), wave owns pt=wv ----
  f32x4 acc2[2];
  {
    #pragma unroll
    for (int ft = 0; ft < 2; ++ft) {
      f32x4 bv;
      #pragma unroll
      for (int r = 0; r < 4; ++r) {
        const int f = ft * 16 + g * 4 + r;
        bv[r] = (f < 25) ? bo[f] : 0.f;
      }
      acc2[ft] = bv;
    }
    __builtin_amdgcn_s_setprio(1);
    #pragma unroll 2
    for (int kc = 0; kc < 12; ++kc) {
      half8 bx = *(const half8*)&hbuf[wv * 6144 + kc * 512 + lane * 8];
      #pragma unroll
      for (int ft = 0; ft < 2; ++ft) {
        half8 aw = *(const half8*)&pwo[(kc * 2 + ft) * 512 + lane * 8];
        acc2[ft] = MFMA32(aw, bx, acc2[ft]);
      }
    }
    __builtin_amdgcn_s_setprio(0);
    __syncthreads();   // all hbuf reads done
  }

  // ---- view-direction encoding -> cols 0..15 (12 real + 4 zero pad) ----
  {
    const int i = t >> 2, q = t & 3;
    const int ray = r0 + i;
    const int sel = selection[ray];
    const float cx = (float)(sel % IMW), cy = (float)(sel / IMW);
    const float* H = wsHs + p * 9;
    const float pr0 = H[0] * cx + H[1] * cy + H[2];
    const float pr1 = H[3] * cx + H[4] * cy + H[5];
    const float pr2 = H[6] * cx + H[7] * cy + H[8];
    const float rx = pr0 / pr2, ry = pr1 / pr2;
    const float pd = planes[p];
    const float* ki = wsKiCam; const float* cam = wsKiCam + 9;
    const float c0 = rx * pd, c1 = ry * pd, c2 = pd;
    const float vx0 = ki[0] * c0 + ki[1] * c1 + ki[2] * c2 - cam[0];
    const float vy0 = ki[3] * c0 + ki[4] * c1 + ki[5] * c2 - cam[1];
    const float vz0 = ki[6] * c0 + ki[7] * c1 + ki[8] * c2 - cam[2];
    const float nrm = sqrtf(vx0 * vx0 + vy0 * vy0 + vz0 * vz0) + 1e-7f;
    const float vx = vx0 / nrm, vy = vy0 / nrm;
    // sin(pi/2 * v * 2^e) = sin_rev(v * 2^(e-2))
    #pragma unroll
    for (int cc = 0; cc < 4; ++cc) {
      const int c = q * 4 + cc;
      float v;
      if (c < 6) {
        v = sin_rev(ldexpf((c < 3) ? vx : vy, (c % 3) - 2));
      } else if (c < 12) {
        const int c6 = c - 6;
        v = sin_rev(ldexpf((c6 < 3) ? vx : vy, (c6 % 3) - 2) + 0.25f);
      } else v = 0.f;
      hbuf[FR(i, c)] = (_Float16)v;
    }
  }
  __syncthreads();   // venc visible to all waves

  // ---- alpha / coeff epilogue from output-layer registers (plane-major) ----
  // (global stores only; overlaps with basis MFMA below — no barrier needed)
  {
    if (g == 0) {   // feature 0 lives in reg r=0 of g=0, ft=0
      const int ray = r0 + wv * 16 + ln;
      wsAlpha[p * RAYS + ray] = sig5_fast(acc2[0][0]);
    }
    if ((p % 12) == 0) {
      const int pg = p / 12;
      const int ray = r0 + wv * 16 + ln;
      #pragma unroll
      for (int ft = 0; ft < 2; ++ft)
        #pragma unroll
        for (int r = 0; r < 4; ++r) {
          const int f = ft * 16 + g * 4 + r;
          if (f >= 1 && f < 25)
            wsCoeff[(pg * 24 + (f - 1)) * RAYS + ray] = tanh_fast(acc2[ft][r]);
        }
    }
  }

  // ---- basis MLP ping-pong: venc(cols0-31) -> 64-127 -> 128-191 -> out ----
  basis_hidden<1>(hbuf, pbw0, bb0, 0, 64, wv, g, ln, lane);
  __syncthreads();
  basis_hidden<2>(hbuf, pbw1, bb1, 2, 128, wv, g, ln, lane);
  __syncthreads();
  {
    f32x4 accO = (f32x4){0.f, 0.f, 0.f, 0.f};
    #pragma unroll
    for (int kc = 0; kc < 2; ++kc) {
      half8 aw = *(const half8*)&pbwo[kc * 512 + lane * 8];
      half8 bx = *(const half8*)&hbuf[wv * 6144 + (4 + kc) * 512 + lane * 8];
      accO = MFMA32(aw, bx, accO);
    }
    if (g < 2) {   // features 0..7; one float4 store per lane, 512B/wave span
      const int ray = r0 + wv * 16 + ln;
      f32x4 bv;
      #pragma unroll
      for (int r = 0; r < 4; ++r)
        bv[r] = tanh_fast(accO[r] + bbo[g * 4 + r]);
      *(f32x4*)&wsBasis[(p * RAYS + ray) * 8 + g * 4] = bv;
    }
  }
}

// ---------------------------------------------------------------------------
// composite: per ray (block, 192 threads = 1 thread/plane):
// grid-sample sigmoid(mpi), illum = coeff . basis, clip, prefix-product scan,
// weighted sum -> out[3][1024]
// ---------------------------------------------------------------------------
__global__ __launch_bounds__(192) void composite_kernel(
    const float* __restrict__ mpi, const int* __restrict__ selection,
    const float* __restrict__ wsHs, const float* __restrict__ wsAlpha,
    const float* __restrict__ wsCoeff, const float* __restrict__ wsBasis,
    float* __restrict__ out)
{
  const int ray = blockIdx.x;
  const int p = threadIdx.x;
  const int sel = selection[ray];
  const float cx = (float)(sel % IMW), cy = (float)(sel / IMW);
  const float* H = wsHs + p * 9;
  const float pr0 = H[0] * cx + H[1] * cy + H[2];
  const float pr1 = H[3] * cx + H[4] * cy + H[5];
  const float pr2 = H[6] * cx + H[7] * cy + H[8];
  const float rx = pr0 / pr2, ry = pr1 / pr2;
  const float wx = (rx / 767.0f) * 2.0f - 1.0f;
  const float wy = (ry / 511.0f) * 2.0f - 1.0f;
  const float x = (wx + 1.0f) * 0.5f * 767.0f;
  const float y = (wy + 1.0f) * 0.5f * 511.0f;
  const float gz = -1.0f + (float)(p / 12) * (2.0f / 15.0f);
  const float z = (gz + 1.0f) * 0.5f * 15.0f;
  const float x0 = floorf(x), y0 = floorf(y), z0 = floorf(z);
  float rgb0 = 0.f, rgb1 = 0.f, rgb2 = 0.f;
  #pragma unroll
  for (int dz = 0; dz < 2; ++dz)
    #pragma unroll
    for (int dy = 0; dy < 2; ++dy)
      #pragma unroll
      for (int dx = 0; dx < 2; ++dx) {
        const float xi = x0 + (float)dx, yi = y0 + (float)dy, zi = z0 + (float)dz;
        const float w = (1.f - fabsf(x - xi)) * (1.f - fabsf(y - yi)) * (1.f - fabsf(z - zi));
        const bool valid = (xi >= 0.f) && (xi < 768.f) && (yi >= 0.f) && (yi < 512.f)
                        && (zi >= 0.f) && (zi < 16.f);
        if (valid && w != 0.f) {
          const int ix = (int)xi, iy = (int)yi, iz = (int)zi;
          const int base = iz * 3 * (IMW * IMH) + iy * IMW + ix;   // mpi[d][c][y][x]
          const float v0 = mpi[base];
          const float v1 = mpi[base + IMW * IMH];
          const float v2 = mpi[base + 2 * IMW * IMH];
          rgb0 += w * (1.f / (1.f + expf(-v0)));
          rgb1 += w * (1.f / (1.f + expf(-v1)));
          rgb2 += w * (1.f / (1.f + expf(-v2)));
        }
      }
  const float* bs = wsBasis + (p * RAYS + ray) * 8;
  const float* cf = wsCoeff + (p / 12) * 24 * RAYS + ray;
  float il0 = 0.f, il1 = 0.f, il2 = 0.f;
  #pragma unroll
  for (int j = 0; j < 8; ++j) {
    const float bj = bs[j];
    il0 += cf[j * RAYS] * bj;
    il1 += cf[(8 + j) * RAYS] * bj;
    il2 += cf[(16 + j) * RAYS] * bj;
  }
  rgb0 = fminf(fmaxf(rgb0 + il0, 0.f), 1.f);
  rgb1 = fminf(fmaxf(rgb1 + il1, 0.f), 1.f);
  rgb2 = fminf(fmaxf(rgb2 + il2, 0.f), 1.f);
  const float a = wsAlpha[p * RAYS + ray];
  const int lane = p & 63, w64 = p >> 6;
  // inclusive prefix product of (1-a) within each wave
  float xs = 1.f - a;
  #pragma unroll
  for (int off = 1; off < 64; off <<= 1) {
    const float v = __shfl_up(xs, off, 64);
    if (lane >= off) xs *= v;
  }
  __shared__ float wtot[3];
  __shared__ float part[3][3];
  if (lane == 63) wtot[w64] = xs;
  __syncthreads();
  float pre = 1.f;
  #pragma unroll
  for (int q = 0; q < 2; ++q)
    if (q < w64) pre *= wtot[q];
  float excl = __shfl_up(xs, 1, 64);
  if (lane == 0) excl = 1.f;
  const float wa = pre * excl * a;
  float s0 = wa * rgb0, s1 = wa * rgb1, s2 = wa * rgb2;
  #pragma unroll
  for (int off = 32; off >= 1; off >>= 1) {
    s0 += __shfl_down(s0, off, 64);
    s1 += __shfl_down(s1, off, 64);
    s2 += __shfl_down(s2, off, 64);
  }
  if (lane == 0) { part[w64][0] = s0; part[w64][1] = s1; part[w64][2] = s2; }
  __syncthreads();
  if (p == 0) {
    out[0 * RAYS + ray] = part[0][0] + part[1][0] + part[2][0];
    out[1 * RAYS + ray] = part[0][1] + part[1][1] + part[2][1];
    out[2 * RAYS + ray] = part[0][2] + part[1][2] + part[2][2];
  }
}

// ---------------------------------------------------------------------------
extern "C" void kernel_launch(void* const* d_in, const int* in_sizes, int n_in,
                              void* d_out, int out_size, void* d_ws, size_t ws_size,
                              hipStream_t stream)
{
  (void)in_sizes; (void)n_in; (void)out_size;
  const float* mpi    = (const float*)d_in[0];
  const float* w0     = (const float*)d_in[1];
  const float* b0     = (const float*)d_in[2];
  const float* w1     = (const float*)d_in[3];
  const float* b1     = (const float*)d_in[4];
  const float* w2     = (const float*)d_in[5];
  const float* b2     = (const float*)d_in[6];
  const float* w3     = (const float*)d_in[7];
  const float* b3     = (const float*)d_in[8];
  const float* w4     = (const float*)d_in[9];
  const float* b4     = (const float*)d_in[10];
  const float* wo     = (const float*)d_in[11];
  const float* bo     = (const float*)d_in[12];
  const float* bw0    = (const float*)d_in[13];
  const float* bb0    = (const float*)d_in[14];
  const float* bw1    = (const float*)d_in[15];
  const float* bb1    = (const float*)d_in[16];
  const float* bwo    = (const float*)d_in[17];
  const float* bbo    = (const float*)d_in[18];
  const float* ref_rT = (const float*)d_in[19];
  const float* ref_t  = (const float*)d_in[20];
  const float* ref_k  = (const float*)d_in[21];
  const float* feat_r = (const float*)d_in[22];
  const float* feat_t = (const float*)d_in[23];
  const float* feat_c = (const float*)d_in[24];
  const float* feat_k = (const float*)d_in[25];
  const float* planes = (const float*)d_in[26];
  const int*   selection = (const int*)d_in[27];
  float* outp = (float*)d_out;
  char* ws = (char*)d_ws;
  if (ws_size < (size_t)WS_NEED) return;   // workspace too small -> visible failure

  float* wsHs    = (float*)(ws + O_HS);
  float* wsKiCam = (float*)(ws + O_KICAM);
  float* wsAlpha = (float*)(ws + O_ALPHA);
  float* wsCoeff = (float*)(ws + O_COEFF);
  float* wsBasis = (float*)(ws + O_BASIS);
  _Float16* pw0  = (_Float16*)(ws + O_PW0);
  _Float16* pw1  = (_Float16*)(ws + O_PW1);
  _Float16* pw2  = (_Float16*)(ws + O_PW2);
  _Float16* pw3  = (_Float16*)(ws + O_PW3);
  _Float16* pw4  = (_Float16*)(ws + O_PW4);
  _Float16* pwo  = (_Float16*)(ws + O_PWO);
  _Float16* pbw0 = (_Float16*)(ws + O_PBW0);
  _Float16* pbw1 = (_Float16*)(ws + O_PBW1);
  _Float16* pbwo = (_Float16*)(ws + O_PBWO);

  pack_all_kernel<<<2476, 256, 0, stream>>>(w0, w1, w2, w3, w4, wo, bw0, bw1, bwo, pw0,
                                            ref_rT, ref_t, ref_k, feat_r, feat_t, feat_c,
                                            feat_k, planes, wsHs, wsKiCam);

  mlp_kernel<<<(NPLANES * RAYS) / 64, 256, 0, stream>>>(
      selection, planes, wsHs, wsKiCam,
      pw0, pw1, pw2, pw3, pw4, pwo,
      b0, b1, b2, b3, b4, bo,
      pbw0, pbw1, pbwo, bb0, bb1, bbo,
      wsAlpha, wsCoeff, wsBasis);

  composite_kernel<<<RAYS, NPLANES, 0, stream>>>(mpi, selection, wsHs, wsAlpha,
                                                 wsCoeff, wsBasis, outp);
}